// Round 2
// baseline (358.497 us; speedup 1.0000x reference)
//
#include <hip/hip_runtime.h>
#include <math.h>

typedef unsigned short u16;
typedef unsigned int   u32;
typedef __attribute__((ext_vector_type(8))) __bf16 bf16x8;
typedef __attribute__((ext_vector_type(4))) float  f32x4;

#define BB 16
#define LL 2048
#define DD 512
#define NF 1025
#define TOPK 4

// ws layout (float-unit offsets), total ~136 MB
static const size_t OFF_XB  = 0;                         // bf16 x row-major [B*L][D]
static const size_t OFF_XTB = OFF_XB  + 8388608;         // bf16 x transposed [B][D][L]
static const size_t OFF_GTB = OFF_XTB + 8388608;         // bf16 G transposed [B][D][L]
static const size_t OFF_XC  = OFF_GTB + 8388608;         // bf16 combined x [B*L][D]
static const size_t OFF_BBM = OFF_XC  + 8388608;         // bf16 Bmat [1024][512]: 0..511=M, 512..1023=Wv
static const size_t OFF_S   = OFF_BBM + 262144;          // spectra [B][NF][2]
static const size_t OFF_W   = OFF_S   + (size_t)BB * NF * 2;
static const size_t OFF_I   = OFF_W   + BB * TOPK;

__device__ __forceinline__ u16 f2bf(float f) {
    u32 u = __float_as_uint(f);
    return (u16)((u + 0x7fffu + ((u >> 16) & 1u)) >> 16);
}
__device__ __forceinline__ float bf2f(u16 h) {
    return __uint_as_float(((u32)h) << 16);
}
__device__ __forceinline__ void gload16(const void* g, void* l) {
    __builtin_amdgcn_global_load_lds((const __attribute__((address_space(1))) void*)g,
                                     (__attribute__((address_space(3))) void*)l, 16, 0, 0);
}
__device__ __forceinline__ float2 cmul(float2 u, float2 v) {
    return make_float2(u.x * v.x - u.y * v.y, u.x * v.y + u.y * v.x);
}
__device__ __forceinline__ float2 cadd(float2 u, float2 v) { return make_float2(u.x + v.x, u.y + v.y); }
__device__ __forceinline__ float2 csub(float2 u, float2 v) { return make_float2(u.x - v.x, u.y - v.y); }

// Bank-conflict-breaking padded index: 1 float2 pad per 32 (max phys 2110 < 2112).
__device__ __forceinline__ int P(int i) { return i + (i >> 5); }

// ---------------------------------------------------------------------------
// Radix-4 Stockham stage, register twiddles (tw[r] = e^{SGN_dir*2pi*i*jm/2048}).
// M=512 has jm==0 always -> identity twiddles, specialized.
template<int M, int SGN>
__device__ __forceinline__ void radix4(const float2* __restrict__ src,
                                       float2* __restrict__ dst,
                                       const float2* __restrict__ tw, int tid) {
#pragma unroll
    for (int r = 0; r < 2; r++) {
        int w = tid + 256 * r;
        int k = w & (M - 1);
        int jm = w - k;
        float2 a = src[P(w)], b = src[P(w + 512)], c = src[P(w + 1024)], d = src[P(w + 1536)];
        float2 t0 = cadd(a, c), t1 = csub(a, c), t2 = cadd(b, d), bd = csub(b, d);
        float2 t3 = (SGN > 0) ? make_float2(bd.y, -bd.x)
                              : make_float2(-bd.y, bd.x);
        int o = 4 * jm + k;
        if (M == 512) {
            dst[P(o)]         = cadd(t0, t2);
            dst[P(o + M)]     = cadd(t1, t3);
            dst[P(o + 2 * M)] = csub(t0, t2);
            dst[P(o + 3 * M)] = csub(t1, t3);
        } else {
            float2 T1 = tw[r];
            float2 T2 = cmul(T1, T1);
            float2 T3 = cmul(T1, T2);
            dst[P(o)]         = cadd(t0, t2);
            dst[P(o + M)]     = cmul(cadd(t1, t3), T1);
            dst[P(o + 2 * M)] = cmul(csub(t0, t2), T2);
            dst[P(o + 3 * M)] = cmul(csub(t1, t3), T3);
        }
    }
}

// 5 radix-4 stages (input must hold the m=2 Stockham state, i.e. after the
// fused radix-2). b1 -> ... -> result in b2. Caller barriers before entry.
template<int SGN>
__device__ __forceinline__ void fft_r4_chain(float2* __restrict__ b1, float2* __restrict__ b2,
                                             const float2 (*tws)[2], int tid) {
    radix4<2,   SGN>(b1, b2, tws[0], tid); __syncthreads();
    radix4<8,   SGN>(b2, b1, tws[1], tid); __syncthreads();
    radix4<32,  SGN>(b1, b2, tws[2], tid); __syncthreads();
    radix4<128, SGN>(b2, b1, tws[3], tid); __syncthreads();
    radix4<512, SGN>(b1, b2, tws[4], tid); __syncthreads();
}

// Per-thread stage twiddles in registers (replaces the LDS twl table).
template<int SGN>
__device__ __forceinline__ void make_tw(float2 tws[5][2], int tid) {
    const float sc = (SGN > 0 ? -6.283185307179586f : 6.283185307179586f) / 2048.0f;
#pragma unroll
    for (int st = 0; st < 5; st++) {
        int M = 2 << (2 * st);   // 2, 8, 32, 128, 512
#pragma unroll
        for (int r = 0; r < 2; r++) {
            int w = tid + 256 * r;
            int jm = w - (w & (M - 1));
            float sn, cs;
            sincosf(sc * (float)jm, &sn, &cs);
            tws[st][r] = make_float2(cs, sn);
        }
    }
}

// ---------------------------------------------------------------------------
// Merged prologue. Branch order matters for dispatch overlap:
//   bid 0..63    : gemm1 M = Wq^T*Wk        (latency-heavy, start FIRST)
//   bid 64..319  : cast Wv + zero S
//   bid 320..4415: transpose+cast x (64x64 tiles, vectorized) — BW-bound bulk
__global__ __launch_bounds__(256) void k_pre(const float* __restrict__ x,
                                             const float* __restrict__ Wq,
                                             const float* __restrict__ Wk,
                                             const float* __restrict__ Wv,
                                             u16* __restrict__ xb,
                                             u16* __restrict__ xtb,
                                             u16* __restrict__ Bm,
                                             float* __restrict__ S) {
    __shared__ char sh[9216];
    int bid = blockIdx.x;
    int tid = threadIdx.x;
    if (bid < 64) {
        // ---- gemm1 branch: M = Wq^T * Wk -> bf16 rows 0..511 of Bmat
        int g = bid;
        float (*As)[68] = (float(*)[68])sh;
        float (*Bs)[68] = (float(*)[68])(sh + 4352);
        int tx = tid & 15, ty = tid >> 4;
        int m0 = (g & 7) * 64, n0 = (g >> 3) * 64;
        float acc[4][4] = {};
        for (int k0 = 0; k0 < DD; k0 += 16) {
#pragma unroll
            for (int r = 0; r < 4; r++) {
                As[ty][tx + 16 * r] = Wq[(size_t)(k0 + ty) * DD + m0 + tx + 16 * r];
                Bs[ty][tx + 16 * r] = Wk[(size_t)(k0 + ty) * DD + n0 + tx + 16 * r];
            }
            __syncthreads();
#pragma unroll
            for (int k = 0; k < 16; k++) {
                float4 a4 = *(const float4*)&As[k][ty * 4];
                float4 b4 = *(const float4*)&Bs[k][tx * 4];
                float a[4] = {a4.x, a4.y, a4.z, a4.w};
                float b[4] = {b4.x, b4.y, b4.z, b4.w};
#pragma unroll
                for (int i = 0; i < 4; i++)
#pragma unroll
                    for (int j = 0; j < 4; j++) acc[i][j] += a[i] * b[j];
            }
            __syncthreads();
        }
#pragma unroll
        for (int i = 0; i < 4; i++) {
            uint2 o;
            o.x = (u32)f2bf(acc[i][0]) | ((u32)f2bf(acc[i][1]) << 16);
            o.y = (u32)f2bf(acc[i][2]) | ((u32)f2bf(acc[i][3]) << 16);
            *(uint2*)&Bm[(size_t)(m0 + ty * 4 + i) * DD + n0 + tx * 4] = o;
        }
    } else if (bid < 320) {
        // ---- misc branch: cast Wv (rows 512..1023 of Bmat), zero S
        int g = bid - 64;                    // 0..255
        int i4 = g * 256 + tid;              // float4 index over 512*512
        float4 w = ((const float4*)Wv)[i4];
        ushort4 o;
        o.x = f2bf(w.x); o.y = f2bf(w.y); o.z = f2bf(w.z); o.w = f2bf(w.w);
        ((ushort4*)(Bm + DD * DD))[i4] = o;
        if (i4 < 8200)                       // 32800 floats = 8200 float4
            ((float4*)S)[i4] = make_float4(0.f, 0.f, 0.f, 0.f);
    } else {
        // ---- transpose branch: x fp32 -> XB bf16 row-major + XTB bf16 transposed
        // 64x64 tile, float4 loads, uint2/uint4 packed stores.
        int tb = bid - 320;                  // 0..4095
        int bx = tb & 7;                     // d-tile (8 x 64)
        int by = (tb >> 3) & 31;             // t-tile (32 x 64)
        int bz = tb >> 8;                    // batch
        u16 (*tile)[72] = (u16(*)[72])sh;    // [d_local][t_local], pitch 72 u16 = 9216 B
        int tx = tid & 15, ty = tid >> 4;    // tx: float4-col in d, ty: row in t
        int d0 = bx * 64, t0 = by * 64;
        const float* ip = x + ((size_t)bz * LL + t0) * DD + d0;
        u16* xbp = xb + ((size_t)bz * LL + t0) * DD + d0;
#pragma unroll
        for (int i = 0; i < 4; i++) {
            int r = ty + 16 * i;
            float4 v = *(const float4*)&ip[(size_t)r * DD + tx * 4];
            uint2 o;
            o.x = (u32)f2bf(v.x) | ((u32)f2bf(v.y) << 16);
            o.y = (u32)f2bf(v.z) | ((u32)f2bf(v.w) << 16);
            *(uint2*)&xbp[(size_t)r * DD + tx * 4] = o;
            tile[tx * 4 + 0][r] = (u16)(o.x);
            tile[tx * 4 + 1][r] = (u16)(o.x >> 16);
            tile[tx * 4 + 2][r] = (u16)(o.y);
            tile[tx * 4 + 3][r] = (u16)(o.y >> 16);
        }
        __syncthreads();
        u16* xtp = xtb + ((size_t)bz * DD + d0) * LL + t0;
#pragma unroll
        for (int i = 0; i < 2; i++) {
            int idx = tid + 256 * i;         // 0..511
            int dr = idx >> 3;               // d row 0..63
            int ch = idx & 7;                // 8-wide t chunk
            uint4 o = *(const uint4*)&tile[dr][ch * 8];
            *(uint4*)&xtp[(size_t)dr * LL + ch * 8] = o;
        }
    }
}

// ---------------------------------------------------------------------------
// G = XB * M^T (bf16 MFMA), written transposed bf16 GTB[b][d][t].
__global__ __launch_bounds__(256, 2) void k_gemm2(const u16* __restrict__ Ab,
                                                  const u16* __restrict__ Bm,
                                                  u16* __restrict__ GTB) {
    __shared__ u16 smem[16384];
    u16* As = smem;
    u16* Bs = smem + 8192;
    int t = threadIdx.x;
    int wave = t >> 6, lane = t & 63;
    int l15 = lane & 15, l4 = lane >> 4;
    int qr = wave & 1, qc = wave >> 1;
    int m0 = blockIdx.x * 128, n0 = blockIdx.y * 128;

    f32x4 acc[4][4];
#pragma unroll
    for (int i = 0; i < 4; i++)
#pragma unroll
        for (int j = 0; j < 4; j++) acc[i][j] = (f32x4){0.f, 0.f, 0.f, 0.f};

    const u16* Ag = Ab + (size_t)m0 * DD;
    const u16* Bg = Bm + (size_t)n0 * DD;
    int a_base = (qr * 64 + l15) * 64 + l4 * 8;
    int b_base = (qc * 64 + l15) * 64 + l4 * 8;

    for (int k0 = 0; k0 < DD; k0 += 64) {
#pragma unroll
        for (int n = 0; n < 4; n++) {
            int c = wave * 256 + n * 64 + lane;
            int row = c >> 3, col = (c & 7) * 8;
            gload16(Ag + (size_t)row * DD + k0 + col, (char*)As + (size_t)(wave * 256 + n * 64) * 16);
            gload16(Bg + (size_t)row * DD + k0 + col, (char*)Bs + (size_t)(wave * 256 + n * 64) * 16);
        }
        __syncthreads();
#pragma unroll
        for (int kk = 0; kk < 64; kk += 32) {
            bf16x8 af[4], bq[4];
#pragma unroll
            for (int i = 0; i < 4; i++) af[i] = *(const bf16x8*)(As + a_base + i * 1024 + kk);
#pragma unroll
            for (int j = 0; j < 4; j++) bq[j] = *(const bf16x8*)(Bs + b_base + j * 1024 + kk);
#pragma unroll
            for (int i = 0; i < 4; i++)
#pragma unroll
                for (int j = 0; j < 4; j++)
                    acc[i][j] = __builtin_amdgcn_mfma_f32_16x16x32_bf16(af[i], bq[j], acc[i][j], 0, 0, 0);
        }
        __syncthreads();
    }

    // Epilogue: transposed bf16 write via swizzled LDS staging
    float4* tb4 = (float4*)smem;
    int bidx = m0 >> 11;
    int tbase = m0 & 2047;
#pragma unroll
    for (int p = 0; p < 2; p++) {
        __syncthreads();
        if (qc == p) {
#pragma unroll
            for (int j = 0; j < 4; j++) {
                int nloc = j * 16 + l15;
#pragma unroll
                for (int i = 0; i < 4; i++) {
                    int tq = qr * 16 + i * 4 + l4;
                    tb4[nloc * 32 + (tq ^ (nloc & 31))] = *(float4*)&acc[i][j];
                }
            }
        }
        __syncthreads();
#pragma unroll
        for (int u = 0; u < 8; u++) {
            int idx4 = u * 256 + t;
            int nloc = idx4 >> 5, c4 = idx4 & 31;
            float4 v = tb4[nloc * 32 + (c4 ^ (nloc & 31))];
            uint2 o;
            o.x = (u32)f2bf(v.x) | ((u32)f2bf(v.y) << 16);
            o.y = (u32)f2bf(v.z) | ((u32)f2bf(v.w) << 16);
            *(uint2*)&GTB[((size_t)bidx * DD + n0 + p * 64 + nloc) * LL + tbase + c4 * 4] = o;
        }
    }
}

// ---------------------------------------------------------------------------
// out = XC * Wv^T + bv (bf16 MFMA), row-major fp32 into d_out.
__global__ __launch_bounds__(256, 2) void k_gemm3(const u16* __restrict__ Ab,
                                                  const u16* __restrict__ Bm,
                                                  const float* __restrict__ bv,
                                                  float* __restrict__ out) {
    __shared__ u16 smem[16384];
    u16* As = smem;
    u16* Bs = smem + 8192;
    int t = threadIdx.x;
    int wave = t >> 6, lane = t & 63;
    int l15 = lane & 15, l4 = lane >> 4;
    int qr = wave & 1, qc = wave >> 1;
    int m0 = blockIdx.x * 128, n0 = blockIdx.y * 128;

    f32x4 acc[4][4];
#pragma unroll
    for (int i = 0; i < 4; i++)
#pragma unroll
        for (int j = 0; j < 4; j++) acc[i][j] = (f32x4){0.f, 0.f, 0.f, 0.f};

    const u16* Ag = Ab + (size_t)m0 * DD;
    const u16* Bg = Bm + (size_t)DD * DD + (size_t)n0 * DD;
    int a_base = (qr * 64 + l15) * 64 + l4 * 8;
    int b_base = (qc * 64 + l15) * 64 + l4 * 8;

    for (int k0 = 0; k0 < DD; k0 += 64) {
#pragma unroll
        for (int n = 0; n < 4; n++) {
            int c = wave * 256 + n * 64 + lane;
            int row = c >> 3, col = (c & 7) * 8;
            gload16(Ag + (size_t)row * DD + k0 + col, (char*)As + (size_t)(wave * 256 + n * 64) * 16);
            gload16(Bg + (size_t)row * DD + k0 + col, (char*)Bs + (size_t)(wave * 256 + n * 64) * 16);
        }
        __syncthreads();
#pragma unroll
        for (int kk = 0; kk < 64; kk += 32) {
            bf16x8 af[4], bq[4];
#pragma unroll
            for (int i = 0; i < 4; i++) af[i] = *(const bf16x8*)(As + a_base + i * 1024 + kk);
#pragma unroll
            for (int j = 0; j < 4; j++) bq[j] = *(const bf16x8*)(Bs + b_base + j * 1024 + kk);
#pragma unroll
            for (int i = 0; i < 4; i++)
#pragma unroll
                for (int j = 0; j < 4; j++)
                    acc[i][j] = __builtin_amdgcn_mfma_f32_16x16x32_bf16(af[i], bq[j], acc[i][j], 0, 0, 0);
        }
        __syncthreads();
    }

    float*  tb  = (float*)smem;
    float4* tb4 = (float4*)smem;
#pragma unroll
    for (int p = 0; p < 2; p++) {
        __syncthreads();
        if (qr == p) {
#pragma unroll
            for (int j = 0; j < 4; j++) {
                int nloc = qc * 64 + j * 16 + l15;
#pragma unroll
                for (int i = 0; i < 4; i++) {
#pragma unroll
                    for (int r = 0; r < 4; r++) {
                        int mloc = i * 16 + l4 * 4 + r;
                        int nc = ((nloc >> 2) ^ (mloc & 31)) << 2;
                        tb[mloc * 128 + nc + (nloc & 3)] = acc[i][j][r];
                    }
                }
            }
        }
        __syncthreads();
#pragma unroll
        for (int u = 0; u < 8; u++) {
            int idx4 = u * 256 + t;
            int mloc = idx4 >> 5, c4 = idx4 & 31;
            float4 v = tb4[mloc * 32 + (c4 ^ (mloc & 31))];
            float4 bias = *(const float4*)&bv[n0 + c4 * 4];
            v.x += bias.x; v.y += bias.y; v.z += bias.z; v.w += bias.w;
            *(float4*)&out[(size_t)(m0 + p * 64 + mloc) * DD + n0 + c4 * 4] = v;
        }
    }
}

// ---------------------------------------------------------------------------
// Per (b, 8-channel group): packed FFT of z = x_d + i*G_d. Radix-2 fused into
// the load phase; 5 radix-4 stages; Hermitian split accumulated in REGISTERS.
// Register twiddles (no LDS table); padded LDS (P) -> no bank conflicts.
// LDS = 33792 B -> 4 blocks/CU; grid 1024 -> full residency.
__global__ __launch_bounds__(256, 4) void k_fft(const u16* __restrict__ XTB,
                                                const u16* __restrict__ GTB,
                                                float* __restrict__ S) {
    __shared__ float2 lds[4224];      // b1[2112] | b2[2112] (padded) = 33792 B
    float2* b1 = lds;
    float2* b2 = lds + 2112;
    int tid = threadIdx.x;
    int grp = blockIdx.x;    // 0..63
    int b = blockIdx.y;

    float2 tws[5][2];
    make_tw<1>(tws, tid);
    float2 tw2[4];
#pragma unroll
    for (int e = 0; e < 4; e++) {
        float sn, cs;
        sincosf(-6.283185307179586f / 2048.0f * (float)(4 * tid + e), &sn, &cs);
        tw2[e] = make_float2(cs, sn);
    }

    float2 sr[4];
#pragma unroll
    for (int r = 0; r < 4; r++) sr[r] = make_float2(0.f, 0.f);
    float s1024 = 0.f;

    for (int c = 0; c < 8; c++) {
        int d = grp * 8 + c;
        const u16* xp = XTB + ((size_t)b * DD + d) * LL;
        const u16* gp = GTB + ((size_t)b * DD + d) * LL;
        // fused load + radix-2: thread t handles j = 4t..4t+3 paired with +1024.
        // Writes b1[P(8t)..P(8t)+7] — contiguous 64 B (never crosses a pad).
        int j0 = 4 * tid;
        uint2 xl = *(const uint2*)&xp[j0];
        uint2 xh = *(const uint2*)&xp[j0 + 1024];
        uint2 gl = *(const uint2*)&gp[j0];
        uint2 gh = *(const uint2*)&gp[j0 + 1024];
        u32 xlw[2] = {xl.x, xl.y}, xhw[2] = {xh.x, xh.y};
        u32 glw[2] = {gl.x, gl.y}, ghw[2] = {gh.x, gh.y};
        float2* wp = &b1[P(8 * tid)];
#pragma unroll
        for (int e = 0; e < 4; e++) {
            int sh = 16 * (e & 1);
            float2 a0 = make_float2(bf2f((u16)(xlw[e >> 1] >> sh)), bf2f((u16)(glw[e >> 1] >> sh)));
            float2 c0 = make_float2(bf2f((u16)(xhw[e >> 1] >> sh)), bf2f((u16)(ghw[e >> 1] >> sh)));
            wp[2 * e]     = cadd(a0, c0);
            wp[2 * e + 1] = cmul(csub(a0, c0), tw2[e]);
        }
        __syncthreads();
        fft_r4_chain<1>(b1, b2, tws, tid);      // result in b2
        // Hermitian split + accumulate S += Xf * conj(Gf)  (registers)
#pragma unroll
        for (int r = 0; r < 4; r++) {
            int f = tid + 256 * r;
            float2 p = b2[P(f)];
            float2 q = b2[P((2048 - f) & 2047)];
            float ar = 0.5f * (p.x + q.x), ai = 0.5f * (p.y - q.y);
            float dr = p.x - q.x, di = p.y + q.y;
            float gr = 0.5f * di, gi = -0.5f * dr;
            sr[r].x += ar * gr + ai * gi;
            sr[r].y += ai * gr - ar * gi;
        }
        if (tid == 0) {
            float2 p = b2[P(1024)];
            s1024 += p.x * p.y;
        }
        // next load writes b1 (safe: last b1 reader barriered inside chain);
        // accumulate reads of b2 complete before next chain's first b2 write
        // (which happens after the post-r2 __syncthreads).
    }
    float* Sg = S + (size_t)b * NF * 2;
#pragma unroll
    for (int r = 0; r < 4; r++) {
        int f = tid + 256 * r;
        atomicAdd(&Sg[2 * f], sr[r].x);
        atomicAdd(&Sg[2 * f + 1], sr[r].y);
    }
    if (tid == 0) {
        atomicAdd(&Sg[2048], s1024);
    }
}

// ---------------------------------------------------------------------------
// Per batch: inverse FFT (fused-r2 load of Hermitian-extended spectrum) ->
// mean_corr, top-4, softmax.
__global__ __launch_bounds__(256) void k_topk(const float* __restrict__ S,
                                              float* __restrict__ wts,
                                              int* __restrict__ idxs) {
    __shared__ float2 lds[4224];
    float2* b1 = lds;
    float2* b2 = lds + 2112;
    __shared__ float cv[2048];
    __shared__ float rv[256];
    __shared__ int ri[256];
    __shared__ float topv[TOPK];
    __shared__ int topi[TOPK];
    int tid = threadIdx.x;
    int b = blockIdx.x;
    const float* Sg = S + (size_t)b * NF * 2;

    float2 tws[5][2];
    make_tw<-1>(tws, tid);

    // fused Hermitian-extension load + radix-2 -> b1 (register twiddles)
#pragma unroll
    for (int h = 0; h < 2; h++) {
#pragma unroll
        for (int e = 0; e < 2; e++) {
            int j = 2 * tid + 512 * h + e;
            float sn, cs;
            sincosf(6.283185307179586f / 2048.0f * (float)j, &sn, &cs);   // inverse sign
            float2 T = make_float2(cs, sn);
            float2 zl = make_float2(Sg[2 * j], Sg[2 * j + 1]);            // j <= 1023
            int fh = j + 1024;
            int ms = 2048 - fh;                                           // mirror for fh>1024
            float2 zh = (fh == 1024) ? make_float2(Sg[2048], Sg[2049])
                                     : make_float2(Sg[2 * ms], -Sg[2 * ms + 1]);
            b1[P(2 * j)]     = cadd(zl, zh);
            b1[P(2 * j + 1)] = cmul(csub(zl, zh), T);
        }
    }
    __syncthreads();
    fft_r4_chain<-1>(b1, b2, tws, tid);   // result in b2
    const float scale = 1.0f / ((float)LL * (float)DD);
    for (int f = tid; f < 2048; f += 256) cv[f] = b2[P(f)].x * scale;
    __syncthreads();
    for (int r = 0; r < TOPK; r++) {
        float best = -3.0e38f;
        int bi = 0x7fffffff;
        for (int f = tid; f < 2048; f += 256) {
            bool taken = false;
            for (int q = 0; q < r; q++) taken |= (topi[q] == f);
            float v = cv[f];
            if (!taken && (v > best || (v == best && f < bi))) { best = v; bi = f; }
        }
        rv[tid] = best; ri[tid] = bi;
        __syncthreads();
        for (int s = 128; s > 0; s >>= 1) {
            if (tid < s) {
                float v2 = rv[tid + s]; int i2 = ri[tid + s];
                if (v2 > rv[tid] || (v2 == rv[tid] && i2 < ri[tid])) { rv[tid] = v2; ri[tid] = i2; }
            }
            __syncthreads();
        }
        if (tid == 0) { topv[r] = rv[0]; topi[r] = ri[0]; }
        __syncthreads();
    }
    if (tid == 0) {
        float mx = topv[0];
        float e[TOPK], sum = 0.f;
        for (int k = 0; k < TOPK; k++) { e[k] = expf(topv[k] - mx); sum += e[k]; }
        for (int k = 0; k < TOPK; k++) {
            wts[b * TOPK + k] = e[k] / sum;
            idxs[b * TOPK + k] = topi[k];
        }
    }
}

// ---------------------------------------------------------------------------
// XC[b,l,:] = round_bf16( sum_k w_k * XB[b,(l-idx_k)&2047,:] )
__global__ __launch_bounds__(128) void k_combine(const u16* __restrict__ XB,
                                                 const float* __restrict__ wts,
                                                 const int* __restrict__ idxs,
                                                 u16* __restrict__ XC) {
    int l = blockIdx.x, b = blockIdx.y;
    int t = threadIdx.x;
    const ushort4* Xb = (const ushort4*)(XB + (size_t)b * LL * DD);
    float4 acc = make_float4(0.f, 0.f, 0.f, 0.f);
#pragma unroll
    for (int k = 0; k < TOPK; k++) {
        float w = wts[b * TOPK + k];
        int r = (l - idxs[b * TOPK + k]) & (LL - 1);
        ushort4 v = Xb[(size_t)r * 128 + t];
        acc.x += w * bf2f(v.x); acc.y += w * bf2f(v.y);
        acc.z += w * bf2f(v.z); acc.w += w * bf2f(v.w);
    }
    ushort4 o;
    o.x = f2bf(acc.x); o.y = f2bf(acc.y); o.z = f2bf(acc.z); o.w = f2bf(acc.w);
    ((ushort4*)(XC + (size_t)b * LL * DD))[(size_t)l * 128 + t] = o;
}

// ---------------------------------------------------------------------------
extern "C" void kernel_launch(void* const* d_in, const int* in_sizes, int n_in,
                              void* d_out, int out_size, void* d_ws, size_t ws_size,
                              hipStream_t stream) {
    const float* x  = (const float*)d_in[0];
    const float* Wq = (const float*)d_in[1];
    const float* Wk = (const float*)d_in[3];
    const float* Wv = (const float*)d_in[5];
    const float* bv = (const float*)d_in[6];
    // bq, bk provably cancel (tau-independent shift; top-k & softmax shift-invariant)
    (void)in_sizes; (void)n_in; (void)out_size; (void)ws_size;

    float* ws  = (float*)d_ws;
    u16*   XB  = (u16*)(ws + OFF_XB);
    u16*   XTB = (u16*)(ws + OFF_XTB);
    u16*   GTB = (u16*)(ws + OFF_GTB);
    u16*   XC  = (u16*)(ws + OFF_XC);
    u16*   BM  = (u16*)(ws + OFF_BBM);
    float* S   = ws + OFF_S;
    float* wts = ws + OFF_W;
    int*   idx = (int*)(ws + OFF_I);
    float* out = (float*)d_out;

    k_pre<<<4416, 256, 0, stream>>>(x, Wq, Wk, Wv, XB, XTB, BM, S);
    k_gemm2<<<dim3((BB * LL) / 128, DD / 128), 256, 0, stream>>>(XB, BM, GTB);
    k_fft<<<dim3(64, BB), 256, 0, stream>>>(XTB, GTB, S);
    k_topk<<<BB, 256, 0, stream>>>(S, wts, idx);
    k_combine<<<dim3(LL, BB), 128, 0, stream>>>(XB, wts, idx, XC);
    k_gemm3<<<dim3((BB * LL) / 128, DD / 128), 256, 0, stream>>>(XC, BM, bv, out);
}

// Round 3
// 348.674 us; speedup vs baseline: 1.0282x; 1.0282x over previous
//
#include <hip/hip_runtime.h>
#include <math.h>

typedef unsigned short u16;
typedef unsigned int   u32;
typedef __attribute__((ext_vector_type(8))) __bf16 bf16x8;
typedef __attribute__((ext_vector_type(4))) float  f32x4;

#define BB 16
#define LL 2048
#define DD 512
#define NF 1025
#define TOPK 4

// ws layout (float-unit offsets), total ~136 MB
static const size_t OFF_XB  = 0;                         // bf16 x row-major [B*L][D]
static const size_t OFF_XTB = OFF_XB  + 8388608;         // bf16 x transposed [B][D][L]
static const size_t OFF_GTB = OFF_XTB + 8388608;         // bf16 G transposed [B][D][L]
static const size_t OFF_XC  = OFF_GTB + 8388608;         // bf16 combined x [B*L][D]
static const size_t OFF_BBM = OFF_XC  + 8388608;         // bf16 Bmat [1024][512]: 0..511=M, 512..1023=Wv
static const size_t OFF_S   = OFF_BBM + 262144;          // spectra [B][NF][2]
static const size_t OFF_W   = OFF_S   + (size_t)BB * NF * 2;
static const size_t OFF_I   = OFF_W   + BB * TOPK;

__device__ __forceinline__ u16 f2bf(float f) {
    u32 u = __float_as_uint(f);
    return (u16)((u + 0x7fffu + ((u >> 16) & 1u)) >> 16);
}
__device__ __forceinline__ float bf2f(u16 h) {
    return __uint_as_float(((u32)h) << 16);
}
__device__ __forceinline__ void gload16(const void* g, void* l) {
    __builtin_amdgcn_global_load_lds((const __attribute__((address_space(1))) void*)g,
                                     (__attribute__((address_space(3))) void*)l, 16, 0, 0);
}
__device__ __forceinline__ float2 cmul(float2 u, float2 v) {
    return make_float2(u.x * v.x - u.y * v.y, u.x * v.y + u.y * v.x);
}
__device__ __forceinline__ float2 cadd(float2 u, float2 v) { return make_float2(u.x + v.x, u.y + v.y); }
__device__ __forceinline__ float2 csub(float2 u, float2 v) { return make_float2(u.x - v.x, u.y - v.y); }

// Bank-conflict-breaking padded index: 1 float2 pad per 32 (max phys 2110 < 2112).
__device__ __forceinline__ int P(int i) { return i + (i >> 5); }

// Register twiddle set: named fields, passed BY VALUE everywhere.
// (R2 lesson: pointer-passing a local array -> scratch spill -> 167 MB of
//  global re-reads per k_fft dispatch. No pointers to locals, ever.)
struct TwSet {
    float2 s0a, s0b;   // M=2
    float2 s1a, s1b;   // M=8
    float2 s2a, s2b;   // M=32
    float2 s3a, s3b;   // M=128  (M=512 is identity-specialized)
};

template<int SGN>
__device__ __forceinline__ float2 tw_of(int M, int r, int tid) {
    const float sc = (SGN > 0 ? -6.283185307179586f : 6.283185307179586f) / 2048.0f;
    int w = tid + 256 * r;
    int jm = w - (w & (M - 1));
    float sn, cs;
    sincosf(sc * (float)jm, &sn, &cs);
    return make_float2(cs, sn);
}

template<int SGN>
__device__ __forceinline__ TwSet make_tw(int tid) {
    TwSet t;
    t.s0a = tw_of<SGN>(2, 0, tid);   t.s0b = tw_of<SGN>(2, 1, tid);
    t.s1a = tw_of<SGN>(8, 0, tid);   t.s1b = tw_of<SGN>(8, 1, tid);
    t.s2a = tw_of<SGN>(32, 0, tid);  t.s2b = tw_of<SGN>(32, 1, tid);
    t.s3a = tw_of<SGN>(128, 0, tid); t.s3b = tw_of<SGN>(128, 1, tid);
    return t;
}

// ---------------------------------------------------------------------------
// Radix-4 Stockham stage, twiddles by value (tw0 for r=0, tw1 for r=1).
// M=512 has jm==0 always -> identity twiddles, specialized.
template<int M, int SGN>
__device__ __forceinline__ void radix4(const float2* __restrict__ src,
                                       float2* __restrict__ dst,
                                       float2 tw0, float2 tw1, int tid) {
#pragma unroll
    for (int r = 0; r < 2; r++) {
        int w = tid + 256 * r;
        int k = w & (M - 1);
        int jm = w - k;
        float2 a = src[P(w)], b = src[P(w + 512)], c = src[P(w + 1024)], d = src[P(w + 1536)];
        float2 t0 = cadd(a, c), t1 = csub(a, c), t2 = cadd(b, d), bd = csub(b, d);
        float2 t3 = (SGN > 0) ? make_float2(bd.y, -bd.x)
                              : make_float2(-bd.y, bd.x);
        int o = 4 * jm + k;
        if (M == 512) {
            dst[P(o)]         = cadd(t0, t2);
            dst[P(o + M)]     = cadd(t1, t3);
            dst[P(o + 2 * M)] = csub(t0, t2);
            dst[P(o + 3 * M)] = csub(t1, t3);
        } else {
            float2 T1 = (r == 0) ? tw0 : tw1;
            float2 T2 = cmul(T1, T1);
            float2 T3 = cmul(T1, T2);
            dst[P(o)]         = cadd(t0, t2);
            dst[P(o + M)]     = cmul(cadd(t1, t3), T1);
            dst[P(o + 2 * M)] = cmul(csub(t0, t2), T2);
            dst[P(o + 3 * M)] = cmul(csub(t1, t3), T3);
        }
    }
}

// 5 radix-4 stages (input must hold the m=2 Stockham state, i.e. after the
// fused radix-2). b1 -> ... -> result in b2. Caller barriers before entry.
template<int SGN>
__device__ __forceinline__ void fft_r4_chain(float2* __restrict__ b1, float2* __restrict__ b2,
                                             TwSet tw, int tid) {
    radix4<2,   SGN>(b1, b2, tw.s0a, tw.s0b, tid); __syncthreads();
    radix4<8,   SGN>(b2, b1, tw.s1a, tw.s1b, tid); __syncthreads();
    radix4<32,  SGN>(b1, b2, tw.s2a, tw.s2b, tid); __syncthreads();
    radix4<128, SGN>(b2, b1, tw.s3a, tw.s3b, tid); __syncthreads();
    radix4<512, SGN>(b1, b2, tw.s0a, tw.s0b, tid); __syncthreads();   // tw unused (identity)
}

// ---------------------------------------------------------------------------
// Merged prologue. Branch order matters for dispatch overlap:
//   bid 0..63    : gemm1 M = Wq^T*Wk        (latency-heavy, start FIRST)
//   bid 64..319  : cast Wv + zero S
//   bid 320..4415: transpose+cast x (64x64 tiles, vectorized) — BW-bound bulk
__global__ __launch_bounds__(256) void k_pre(const float* __restrict__ x,
                                             const float* __restrict__ Wq,
                                             const float* __restrict__ Wk,
                                             const float* __restrict__ Wv,
                                             u16* __restrict__ xb,
                                             u16* __restrict__ xtb,
                                             u16* __restrict__ Bm,
                                             float* __restrict__ S) {
    __shared__ char sh[9216];
    int bid = blockIdx.x;
    int tid = threadIdx.x;
    if (bid < 64) {
        // ---- gemm1 branch: M = Wq^T * Wk -> bf16 rows 0..511 of Bmat
        int g = bid;
        float (*As)[68] = (float(*)[68])sh;
        float (*Bs)[68] = (float(*)[68])(sh + 4352);
        int tx = tid & 15, ty = tid >> 4;
        int m0 = (g & 7) * 64, n0 = (g >> 3) * 64;
        float acc[4][4] = {};
        for (int k0 = 0; k0 < DD; k0 += 16) {
#pragma unroll
            for (int r = 0; r < 4; r++) {
                As[ty][tx + 16 * r] = Wq[(size_t)(k0 + ty) * DD + m0 + tx + 16 * r];
                Bs[ty][tx + 16 * r] = Wk[(size_t)(k0 + ty) * DD + n0 + tx + 16 * r];
            }
            __syncthreads();
#pragma unroll
            for (int k = 0; k < 16; k++) {
                float4 a4 = *(const float4*)&As[k][ty * 4];
                float4 b4 = *(const float4*)&Bs[k][tx * 4];
                float a[4] = {a4.x, a4.y, a4.z, a4.w};
                float b[4] = {b4.x, b4.y, b4.z, b4.w};
#pragma unroll
                for (int i = 0; i < 4; i++)
#pragma unroll
                    for (int j = 0; j < 4; j++) acc[i][j] += a[i] * b[j];
            }
            __syncthreads();
        }
#pragma unroll
        for (int i = 0; i < 4; i++) {
            uint2 o;
            o.x = (u32)f2bf(acc[i][0]) | ((u32)f2bf(acc[i][1]) << 16);
            o.y = (u32)f2bf(acc[i][2]) | ((u32)f2bf(acc[i][3]) << 16);
            *(uint2*)&Bm[(size_t)(m0 + ty * 4 + i) * DD + n0 + tx * 4] = o;
        }
    } else if (bid < 320) {
        // ---- misc branch: cast Wv (rows 512..1023 of Bmat), zero S
        int g = bid - 64;                    // 0..255
        int i4 = g * 256 + tid;              // float4 index over 512*512
        float4 w = ((const float4*)Wv)[i4];
        ushort4 o;
        o.x = f2bf(w.x); o.y = f2bf(w.y); o.z = f2bf(w.z); o.w = f2bf(w.w);
        ((ushort4*)(Bm + DD * DD))[i4] = o;
        if (i4 < 8200)                       // 32800 floats = 8200 float4
            ((float4*)S)[i4] = make_float4(0.f, 0.f, 0.f, 0.f);
    } else {
        // ---- transpose branch: x fp32 -> XB bf16 row-major + XTB bf16 transposed
        // 64x64 tile, float4 loads, uint2/uint4 packed stores.
        int tb = bid - 320;                  // 0..4095
        int bx = tb & 7;                     // d-tile (8 x 64)
        int by = (tb >> 3) & 31;             // t-tile (32 x 64)
        int bz = tb >> 8;                    // batch
        u16 (*tile)[72] = (u16(*)[72])sh;    // [d_local][t_local], pitch 72 u16 = 9216 B
        int tx = tid & 15, ty = tid >> 4;    // tx: float4-col in d, ty: row in t
        int d0 = bx * 64, t0 = by * 64;
        const float* ip = x + ((size_t)bz * LL + t0) * DD + d0;
        u16* xbp = xb + ((size_t)bz * LL + t0) * DD + d0;
#pragma unroll
        for (int i = 0; i < 4; i++) {
            int r = ty + 16 * i;
            float4 v = *(const float4*)&ip[(size_t)r * DD + tx * 4];
            uint2 o;
            o.x = (u32)f2bf(v.x) | ((u32)f2bf(v.y) << 16);
            o.y = (u32)f2bf(v.z) | ((u32)f2bf(v.w) << 16);
            *(uint2*)&xbp[(size_t)r * DD + tx * 4] = o;
            tile[tx * 4 + 0][r] = (u16)(o.x);
            tile[tx * 4 + 1][r] = (u16)(o.x >> 16);
            tile[tx * 4 + 2][r] = (u16)(o.y);
            tile[tx * 4 + 3][r] = (u16)(o.y >> 16);
        }
        __syncthreads();
        u16* xtp = xtb + ((size_t)bz * DD + d0) * LL + t0;
#pragma unroll
        for (int i = 0; i < 2; i++) {
            int idx = tid + 256 * i;         // 0..511
            int dr = idx >> 3;               // d row 0..63
            int ch = idx & 7;                // 8-wide t chunk
            uint4 o = *(const uint4*)&tile[dr][ch * 8];
            *(uint4*)&xtp[(size_t)dr * LL + ch * 8] = o;
        }
    }
}

// ---------------------------------------------------------------------------
// G = XB * M^T (bf16 MFMA), written transposed bf16 GTB[b][d][t].
__global__ __launch_bounds__(256, 2) void k_gemm2(const u16* __restrict__ Ab,
                                                  const u16* __restrict__ Bm,
                                                  u16* __restrict__ GTB) {
    __shared__ u16 smem[16384];
    u16* As = smem;
    u16* Bs = smem + 8192;
    int t = threadIdx.x;
    int wave = t >> 6, lane = t & 63;
    int l15 = lane & 15, l4 = lane >> 4;
    int qr = wave & 1, qc = wave >> 1;
    int m0 = blockIdx.x * 128, n0 = blockIdx.y * 128;

    f32x4 acc[4][4];
#pragma unroll
    for (int i = 0; i < 4; i++)
#pragma unroll
        for (int j = 0; j < 4; j++) acc[i][j] = (f32x4){0.f, 0.f, 0.f, 0.f};

    const u16* Ag = Ab + (size_t)m0 * DD;
    const u16* Bg = Bm + (size_t)n0 * DD;
    int a_base = (qr * 64 + l15) * 64 + l4 * 8;
    int b_base = (qc * 64 + l15) * 64 + l4 * 8;

    for (int k0 = 0; k0 < DD; k0 += 64) {
#pragma unroll
        for (int n = 0; n < 4; n++) {
            int c = wave * 256 + n * 64 + lane;
            int row = c >> 3, col = (c & 7) * 8;
            gload16(Ag + (size_t)row * DD + k0 + col, (char*)As + (size_t)(wave * 256 + n * 64) * 16);
            gload16(Bg + (size_t)row * DD + k0 + col, (char*)Bs + (size_t)(wave * 256 + n * 64) * 16);
        }
        __syncthreads();
#pragma unroll
        for (int kk = 0; kk < 64; kk += 32) {
            bf16x8 af[4], bq[4];
#pragma unroll
            for (int i = 0; i < 4; i++) af[i] = *(const bf16x8*)(As + a_base + i * 1024 + kk);
#pragma unroll
            for (int j = 0; j < 4; j++) bq[j] = *(const bf16x8*)(Bs + b_base + j * 1024 + kk);
#pragma unroll
            for (int i = 0; i < 4; i++)
#pragma unroll
                for (int j = 0; j < 4; j++)
                    acc[i][j] = __builtin_amdgcn_mfma_f32_16x16x32_bf16(af[i], bq[j], acc[i][j], 0, 0, 0);
        }
        __syncthreads();
    }

    // Epilogue: transposed bf16 write via swizzled LDS staging
    float4* tb4 = (float4*)smem;
    int bidx = m0 >> 11;
    int tbase = m0 & 2047;
#pragma unroll
    for (int p = 0; p < 2; p++) {
        __syncthreads();
        if (qc == p) {
#pragma unroll
            for (int j = 0; j < 4; j++) {
                int nloc = j * 16 + l15;
#pragma unroll
                for (int i = 0; i < 4; i++) {
                    int tq = qr * 16 + i * 4 + l4;
                    tb4[nloc * 32 + (tq ^ (nloc & 31))] = *(float4*)&acc[i][j];
                }
            }
        }
        __syncthreads();
#pragma unroll
        for (int u = 0; u < 8; u++) {
            int idx4 = u * 256 + t;
            int nloc = idx4 >> 5, c4 = idx4 & 31;
            float4 v = tb4[nloc * 32 + (c4 ^ (nloc & 31))];
            uint2 o;
            o.x = (u32)f2bf(v.x) | ((u32)f2bf(v.y) << 16);
            o.y = (u32)f2bf(v.z) | ((u32)f2bf(v.w) << 16);
            *(uint2*)&GTB[((size_t)bidx * DD + n0 + p * 64 + nloc) * LL + tbase + c4 * 4] = o;
        }
    }
}

// ---------------------------------------------------------------------------
// out = XC * Wv^T + bv (bf16 MFMA), row-major fp32 into d_out.
__global__ __launch_bounds__(256, 2) void k_gemm3(const u16* __restrict__ Ab,
                                                  const u16* __restrict__ Bm,
                                                  const float* __restrict__ bv,
                                                  float* __restrict__ out) {
    __shared__ u16 smem[16384];
    u16* As = smem;
    u16* Bs = smem + 8192;
    int t = threadIdx.x;
    int wave = t >> 6, lane = t & 63;
    int l15 = lane & 15, l4 = lane >> 4;
    int qr = wave & 1, qc = wave >> 1;
    int m0 = blockIdx.x * 128, n0 = blockIdx.y * 128;

    f32x4 acc[4][4];
#pragma unroll
    for (int i = 0; i < 4; i++)
#pragma unroll
        for (int j = 0; j < 4; j++) acc[i][j] = (f32x4){0.f, 0.f, 0.f, 0.f};

    const u16* Ag = Ab + (size_t)m0 * DD;
    const u16* Bg = Bm + (size_t)DD * DD + (size_t)n0 * DD;
    int a_base = (qr * 64 + l15) * 64 + l4 * 8;
    int b_base = (qc * 64 + l15) * 64 + l4 * 8;

    for (int k0 = 0; k0 < DD; k0 += 64) {
#pragma unroll
        for (int n = 0; n < 4; n++) {
            int c = wave * 256 + n * 64 + lane;
            int row = c >> 3, col = (c & 7) * 8;
            gload16(Ag + (size_t)row * DD + k0 + col, (char*)As + (size_t)(wave * 256 + n * 64) * 16);
            gload16(Bg + (size_t)row * DD + k0 + col, (char*)Bs + (size_t)(wave * 256 + n * 64) * 16);
        }
        __syncthreads();
#pragma unroll
        for (int kk = 0; kk < 64; kk += 32) {
            bf16x8 af[4], bq[4];
#pragma unroll
            for (int i = 0; i < 4; i++) af[i] = *(const bf16x8*)(As + a_base + i * 1024 + kk);
#pragma unroll
            for (int j = 0; j < 4; j++) bq[j] = *(const bf16x8*)(Bs + b_base + j * 1024 + kk);
#pragma unroll
            for (int i = 0; i < 4; i++)
#pragma unroll
                for (int j = 0; j < 4; j++)
                    acc[i][j] = __builtin_amdgcn_mfma_f32_16x16x32_bf16(af[i], bq[j], acc[i][j], 0, 0, 0);
        }
        __syncthreads();
    }

    float*  tb  = (float*)smem;
    float4* tb4 = (float4*)smem;
#pragma unroll
    for (int p = 0; p < 2; p++) {
        __syncthreads();
        if (qr == p) {
#pragma unroll
            for (int j = 0; j < 4; j++) {
                int nloc = qc * 64 + j * 16 + l15;
#pragma unroll
                for (int i = 0; i < 4; i++) {
#pragma unroll
                    for (int r = 0; r < 4; r++) {
                        int mloc = i * 16 + l4 * 4 + r;
                        int nc = ((nloc >> 2) ^ (mloc & 31)) << 2;
                        tb[mloc * 128 + nc + (nloc & 3)] = acc[i][j][r];
                    }
                }
            }
        }
        __syncthreads();
#pragma unroll
        for (int u = 0; u < 8; u++) {
            int idx4 = u * 256 + t;
            int mloc = idx4 >> 5, c4 = idx4 & 31;
            float4 v = tb4[mloc * 32 + (c4 ^ (mloc & 31))];
            float4 bias = *(const float4*)&bv[n0 + c4 * 4];
            v.x += bias.x; v.y += bias.y; v.z += bias.z; v.w += bias.w;
            *(float4*)&out[(size_t)(m0 + p * 64 + mloc) * DD + n0 + c4 * 4] = v;
        }
    }
}

// ---------------------------------------------------------------------------
// Per (b, 8-channel group): packed FFT of z = x_d + i*G_d. Radix-2 fused into
// the load phase; 5 radix-4 stages; Hermitian split accumulated in REGISTERS.
// Register twiddles BY VALUE (no LDS table, no scratch); padded LDS (P).
// LDS = 33792 B -> 4 blocks/CU; grid 1024 -> full residency.
__global__ __launch_bounds__(256, 4) void k_fft(const u16* __restrict__ XTB,
                                                const u16* __restrict__ GTB,
                                                float* __restrict__ S) {
    __shared__ float2 lds[4224];      // b1[2112] | b2[2112] (padded) = 33792 B
    float2* b1 = lds;
    float2* b2 = lds + 2112;
    int tid = threadIdx.x;
    int grp = blockIdx.x;    // 0..63
    int b = blockIdx.y;

    TwSet tws = make_tw<1>(tid);
    float2 tw2a, tw2b, tw2c, tw2d;
    {
        float sn, cs;
        sincosf(-6.283185307179586f / 2048.0f * (float)(4 * tid + 0), &sn, &cs); tw2a = make_float2(cs, sn);
        sincosf(-6.283185307179586f / 2048.0f * (float)(4 * tid + 1), &sn, &cs); tw2b = make_float2(cs, sn);
        sincosf(-6.283185307179586f / 2048.0f * (float)(4 * tid + 2), &sn, &cs); tw2c = make_float2(cs, sn);
        sincosf(-6.283185307179586f / 2048.0f * (float)(4 * tid + 3), &sn, &cs); tw2d = make_float2(cs, sn);
    }

    float2 sr[4];
#pragma unroll
    for (int r = 0; r < 4; r++) sr[r] = make_float2(0.f, 0.f);
    float s1024 = 0.f;

    for (int c = 0; c < 8; c++) {
        int d = grp * 8 + c;
        const u16* xp = XTB + ((size_t)b * DD + d) * LL;
        const u16* gp = GTB + ((size_t)b * DD + d) * LL;
        // fused load + radix-2: thread t handles j = 4t..4t+3 paired with +1024.
        // Writes b1[P(8t)..P(8t)+7] — contiguous 64 B (never crosses a pad).
        int j0 = 4 * tid;
        uint2 xl = *(const uint2*)&xp[j0];
        uint2 xh = *(const uint2*)&xp[j0 + 1024];
        uint2 gl = *(const uint2*)&gp[j0];
        uint2 gh = *(const uint2*)&gp[j0 + 1024];
        float2* wp = &b1[P(8 * tid)];
        {
            float2 a0 = make_float2(bf2f((u16)xl.x), bf2f((u16)gl.x));
            float2 c0 = make_float2(bf2f((u16)xh.x), bf2f((u16)gh.x));
            wp[0] = cadd(a0, c0);
            wp[1] = cmul(csub(a0, c0), tw2a);
            float2 a1 = make_float2(bf2f((u16)(xl.x >> 16)), bf2f((u16)(gl.x >> 16)));
            float2 c1 = make_float2(bf2f((u16)(xh.x >> 16)), bf2f((u16)(gh.x >> 16)));
            wp[2] = cadd(a1, c1);
            wp[3] = cmul(csub(a1, c1), tw2b);
            float2 a2 = make_float2(bf2f((u16)xl.y), bf2f((u16)gl.y));
            float2 c2 = make_float2(bf2f((u16)xh.y), bf2f((u16)gh.y));
            wp[4] = cadd(a2, c2);
            wp[5] = cmul(csub(a2, c2), tw2c);
            float2 a3 = make_float2(bf2f((u16)(xl.y >> 16)), bf2f((u16)(gl.y >> 16)));
            float2 c3 = make_float2(bf2f((u16)(xh.y >> 16)), bf2f((u16)(gh.y >> 16)));
            wp[6] = cadd(a3, c3);
            wp[7] = cmul(csub(a3, c3), tw2d);
        }
        __syncthreads();
        fft_r4_chain<1>(b1, b2, tws, tid);      // result in b2
        // Hermitian split + accumulate S += Xf * conj(Gf)  (registers)
#pragma unroll
        for (int r = 0; r < 4; r++) {
            int f = tid + 256 * r;
            float2 p = b2[P(f)];
            float2 q = b2[P((2048 - f) & 2047)];
            float ar = 0.5f * (p.x + q.x), ai = 0.5f * (p.y - q.y);
            float dr = p.x - q.x, di = p.y + q.y;
            float gr = 0.5f * di, gi = -0.5f * dr;
            sr[r].x += ar * gr + ai * gi;
            sr[r].y += ai * gr - ar * gi;
        }
        if (tid == 0) {
            float2 p = b2[P(1024)];
            s1024 += p.x * p.y;
        }
        // next load writes b1 (safe: last b1 reader barriered inside chain);
        // accumulate reads of b2 complete before next chain's first b2 write
        // (which happens after the post-r2 __syncthreads).
    }
    float* Sg = S + (size_t)b * NF * 2;
#pragma unroll
    for (int r = 0; r < 4; r++) {
        int f = tid + 256 * r;
        atomicAdd(&Sg[2 * f], sr[r].x);
        atomicAdd(&Sg[2 * f + 1], sr[r].y);
    }
    if (tid == 0) {
        atomicAdd(&Sg[2048], s1024);
    }
}

// ---------------------------------------------------------------------------
// Per batch: inverse FFT (fused-r2 load of Hermitian-extended spectrum) ->
// mean_corr, top-4, softmax.
__global__ __launch_bounds__(256) void k_topk(const float* __restrict__ S,
                                              float* __restrict__ wts,
                                              int* __restrict__ idxs) {
    __shared__ float2 lds[4224];
    float2* b1 = lds;
    float2* b2 = lds + 2112;
    __shared__ float cv[2048];
    __shared__ float rv[256];
    __shared__ int ri[256];
    __shared__ float topv[TOPK];
    __shared__ int topi[TOPK];
    int tid = threadIdx.x;
    int b = blockIdx.x;
    const float* Sg = S + (size_t)b * NF * 2;

    TwSet tws = make_tw<-1>(tid);

    // fused Hermitian-extension load + radix-2 -> b1 (register twiddles)
#pragma unroll
    for (int h = 0; h < 2; h++) {
#pragma unroll
        for (int e = 0; e < 2; e++) {
            int j = 2 * tid + 512 * h + e;
            float sn, cs;
            sincosf(6.283185307179586f / 2048.0f * (float)j, &sn, &cs);   // inverse sign
            float2 T = make_float2(cs, sn);
            float2 zl = make_float2(Sg[2 * j], Sg[2 * j + 1]);            // j <= 1023
            int fh = j + 1024;
            int ms = 2048 - fh;                                           // mirror for fh>1024
            float2 zh = (fh == 1024) ? make_float2(Sg[2048], Sg[2049])
                                     : make_float2(Sg[2 * ms], -Sg[2 * ms + 1]);
            b1[P(2 * j)]     = cadd(zl, zh);
            b1[P(2 * j + 1)] = cmul(csub(zl, zh), T);
        }
    }
    __syncthreads();
    fft_r4_chain<-1>(b1, b2, tws, tid);   // result in b2
    const float scale = 1.0f / ((float)LL * (float)DD);
    for (int f = tid; f < 2048; f += 256) cv[f] = b2[P(f)].x * scale;
    __syncthreads();
    for (int r = 0; r < TOPK; r++) {
        float best = -3.0e38f;
        int bi = 0x7fffffff;
        for (int f = tid; f < 2048; f += 256) {
            bool taken = false;
            for (int q = 0; q < r; q++) taken |= (topi[q] == f);
            float v = cv[f];
            if (!taken && (v > best || (v == best && f < bi))) { best = v; bi = f; }
        }
        rv[tid] = best; ri[tid] = bi;
        __syncthreads();
        for (int s = 128; s > 0; s >>= 1) {
            if (tid < s) {
                float v2 = rv[tid + s]; int i2 = ri[tid + s];
                if (v2 > rv[tid] || (v2 == rv[tid] && i2 < ri[tid])) { rv[tid] = v2; ri[tid] = i2; }
            }
            __syncthreads();
        }
        if (tid == 0) { topv[r] = rv[0]; topi[r] = ri[0]; }
        __syncthreads();
    }
    if (tid == 0) {
        float mx = topv[0];
        float e[TOPK], sum = 0.f;
        for (int k = 0; k < TOPK; k++) { e[k] = expf(topv[k] - mx); sum += e[k]; }
        for (int k = 0; k < TOPK; k++) {
            wts[b * TOPK + k] = e[k] / sum;
            idxs[b * TOPK + k] = topi[k];
        }
    }
}

// ---------------------------------------------------------------------------
// XC[b,l,:] = round_bf16( sum_k w_k * XB[b,(l-idx_k)&2047,:] )
__global__ __launch_bounds__(128) void k_combine(const u16* __restrict__ XB,
                                                 const float* __restrict__ wts,
                                                 const int* __restrict__ idxs,
                                                 u16* __restrict__ XC) {
    int l = blockIdx.x, b = blockIdx.y;
    int t = threadIdx.x;
    const ushort4* Xb = (const ushort4*)(XB + (size_t)b * LL * DD);
    float4 acc = make_float4(0.f, 0.f, 0.f, 0.f);
#pragma unroll
    for (int k = 0; k < TOPK; k++) {
        float w = wts[b * TOPK + k];
        int r = (l - idxs[b * TOPK + k]) & (LL - 1);
        ushort4 v = Xb[(size_t)r * 128 + t];
        acc.x += w * bf2f(v.x); acc.y += w * bf2f(v.y);
        acc.z += w * bf2f(v.z); acc.w += w * bf2f(v.w);
    }
    ushort4 o;
    o.x = f2bf(acc.x); o.y = f2bf(acc.y); o.z = f2bf(acc.z); o.w = f2bf(acc.w);
    ((ushort4*)(XC + (size_t)b * LL * DD))[(size_t)l * 128 + t] = o;
}

// ---------------------------------------------------------------------------
extern "C" void kernel_launch(void* const* d_in, const int* in_sizes, int n_in,
                              void* d_out, int out_size, void* d_ws, size_t ws_size,
                              hipStream_t stream) {
    const float* x  = (const float*)d_in[0];
    const float* Wq = (const float*)d_in[1];
    const float* Wk = (const float*)d_in[3];
    const float* Wv = (const float*)d_in[5];
    const float* bv = (const float*)d_in[6];
    // bq, bk provably cancel (tau-independent shift; top-k & softmax shift-invariant)
    (void)in_sizes; (void)n_in; (void)out_size; (void)ws_size;

    float* ws  = (float*)d_ws;
    u16*   XB  = (u16*)(ws + OFF_XB);
    u16*   XTB = (u16*)(ws + OFF_XTB);
    u16*   GTB = (u16*)(ws + OFF_GTB);
    u16*   XC  = (u16*)(ws + OFF_XC);
    u16*   BM  = (u16*)(ws + OFF_BBM);
    float* S   = ws + OFF_S;
    float* wts = ws + OFF_W;
    int*   idx = (int*)(ws + OFF_I);
    float* out = (float*)d_out;

    k_pre<<<4416, 256, 0, stream>>>(x, Wq, Wk, Wv, XB, XTB, BM, S);
    k_gemm2<<<dim3((BB * LL) / 128, DD / 128), 256, 0, stream>>>(XB, BM, GTB);
    k_fft<<<dim3(64, BB), 256, 0, stream>>>(XTB, GTB, S);
    k_topk<<<BB, 256, 0, stream>>>(S, wts, idx);
    k_combine<<<dim3(LL, BB), 128, 0, stream>>>(XB, wts, idx, XC);
    k_gemm3<<<dim3((BB * LL) / 128, DD / 128), 256, 0, stream>>>(XC, BM, bv, out);
}

// Round 4
// 310.798 us; speedup vs baseline: 1.1535x; 1.1219x over previous
//
#include <hip/hip_runtime.h>
#include <math.h>

typedef unsigned short u16;
typedef unsigned int   u32;
typedef __attribute__((ext_vector_type(8))) __bf16 bf16x8;
typedef __attribute__((ext_vector_type(4))) float  f32x4;

#define BB 16
#define LL 2048
#define DD 512
#define NF 1025
#define TOPK 4

// ws layout (float-unit offsets), total ~136 MB
static const size_t OFF_XB  = 0;                         // bf16 x row-major [B*L][D]
static const size_t OFF_XTB = OFF_XB  + 8388608;         // bf16 x transposed [B][D][L]
static const size_t OFF_GTB = OFF_XTB + 8388608;         // bf16 G transposed [B][D][L]
static const size_t OFF_XC  = OFF_GTB + 8388608;         // bf16 combined x [B*L][D]
static const size_t OFF_BBM = OFF_XC  + 8388608;         // bf16 Bmat [1024][512]: 0..511=M, 512..1023=Wv
static const size_t OFF_S   = OFF_BBM + 262144;          // spectra [B][NF][2]
static const size_t OFF_W   = OFF_S   + (size_t)BB * NF * 2;
static const size_t OFF_I   = OFF_W   + BB * TOPK;

__device__ __forceinline__ u16 f2bf(float f) {
    u32 u = __float_as_uint(f);
    return (u16)((u + 0x7fffu + ((u >> 16) & 1u)) >> 16);
}
__device__ __forceinline__ float bf2f(u16 h) {
    return __uint_as_float(((u32)h) << 16);
}
__device__ __forceinline__ void gload16(const void* g, void* l) {
    __builtin_amdgcn_global_load_lds((const __attribute__((address_space(1))) void*)g,
                                     (__attribute__((address_space(3))) void*)l, 16, 0, 0);
}
__device__ __forceinline__ float2 cmul(float2 u, float2 v) {
    return make_float2(u.x * v.x - u.y * v.y, u.x * v.y + u.y * v.x);
}
__device__ __forceinline__ float2 cadd(float2 u, float2 v) { return make_float2(u.x + v.x, u.y + v.y); }
__device__ __forceinline__ float2 csub(float2 u, float2 v) { return make_float2(u.x - v.x, u.y - v.y); }

// Bank-conflict-breaking padded index (1 pad per 8 float2). Verified against
// every Stockham access: M=2 store -> 9q+s (2 lanes/bank-pair), M=8 store ->
// 36h+k == 4h+k mod 32 (2 reps/residue), all other stages consecutive. Free.
__device__ __forceinline__ int P(int i) { return i + (i >> 3); }

// ---------------------------------------------------------------------------
// Radix-4 Stockham stage. Twiddles from a 512-entry LDS table (jm <= 511
// always, since w <= 511). M=512 has jm==0 -> identity, specialized.
// (R2/R3 lesson: register-resident twiddle sets live across the barriered
//  channel loop spill to scratch -> 70-130 MB of HBM traffic. LDS table is
//  the proven-clean mechanism.)
template<int M, int SGN>
__device__ __forceinline__ void radix4(const float2* __restrict__ src,
                                       float2* __restrict__ dst,
                                       const float2* __restrict__ twl, int tid) {
#pragma unroll
    for (int r = 0; r < 2; r++) {
        int w = tid + 256 * r;
        int k = w & (M - 1);
        int jm = w - k;
        float2 a = src[P(w)], b = src[P(w + 512)], c = src[P(w + 1024)], d = src[P(w + 1536)];
        float2 t0 = cadd(a, c), t1 = csub(a, c), t2 = cadd(b, d), bd = csub(b, d);
        float2 t3 = (SGN > 0) ? make_float2(bd.y, -bd.x)
                              : make_float2(-bd.y, bd.x);
        int o = 4 * jm + k;
        if (M == 512) {
            dst[P(o)]         = cadd(t0, t2);
            dst[P(o + M)]     = cadd(t1, t3);
            dst[P(o + 2 * M)] = csub(t0, t2);
            dst[P(o + 3 * M)] = csub(t1, t3);
        } else {
            float2 T1 = twl[jm];
            float2 T2 = cmul(T1, T1);
            float2 T3 = cmul(T1, T2);
            dst[P(o)]         = cadd(t0, t2);
            dst[P(o + M)]     = cmul(cadd(t1, t3), T1);
            dst[P(o + 2 * M)] = cmul(csub(t0, t2), T2);
            dst[P(o + 3 * M)] = cmul(csub(t1, t3), T3);
        }
    }
}

// 5 radix-4 stages (input must hold the m=2 Stockham state, i.e. after the
// fused radix-2). b1 -> ... -> result in b2. Caller barriers before entry.
template<int SGN>
__device__ __forceinline__ void fft_r4_chain(float2* __restrict__ b1, float2* __restrict__ b2,
                                             const float2* __restrict__ twl, int tid) {
    radix4<2,   SGN>(b1, b2, twl, tid); __syncthreads();
    radix4<8,   SGN>(b2, b1, twl, tid); __syncthreads();
    radix4<32,  SGN>(b1, b2, twl, tid); __syncthreads();
    radix4<128, SGN>(b2, b1, twl, tid); __syncthreads();
    radix4<512, SGN>(b1, b2, twl, tid); __syncthreads();
}

// ---------------------------------------------------------------------------
// Merged prologue. Branch order matters for dispatch overlap:
//   bid 0..63    : gemm1 M = Wq^T*Wk        (latency-heavy, start FIRST)
//   bid 64..319  : cast Wv + zero S
//   bid 320..4415: transpose+cast x (64x64 tiles, vectorized) — BW-bound bulk
__global__ __launch_bounds__(256) void k_pre(const float* __restrict__ x,
                                             const float* __restrict__ Wq,
                                             const float* __restrict__ Wk,
                                             const float* __restrict__ Wv,
                                             u16* __restrict__ xb,
                                             u16* __restrict__ xtb,
                                             u16* __restrict__ Bm,
                                             float* __restrict__ S) {
    __shared__ char sh[9216];
    int bid = blockIdx.x;
    int tid = threadIdx.x;
    if (bid < 64) {
        // ---- gemm1 branch: M = Wq^T * Wk -> bf16 rows 0..511 of Bmat
        int g = bid;
        float (*As)[68] = (float(*)[68])sh;
        float (*Bs)[68] = (float(*)[68])(sh + 4352);
        int tx = tid & 15, ty = tid >> 4;
        int m0 = (g & 7) * 64, n0 = (g >> 3) * 64;
        float acc[4][4] = {};
        for (int k0 = 0; k0 < DD; k0 += 16) {
#pragma unroll
            for (int r = 0; r < 4; r++) {
                As[ty][tx + 16 * r] = Wq[(size_t)(k0 + ty) * DD + m0 + tx + 16 * r];
                Bs[ty][tx + 16 * r] = Wk[(size_t)(k0 + ty) * DD + n0 + tx + 16 * r];
            }
            __syncthreads();
#pragma unroll
            for (int k = 0; k < 16; k++) {
                float4 a4 = *(const float4*)&As[k][ty * 4];
                float4 b4 = *(const float4*)&Bs[k][tx * 4];
                float a[4] = {a4.x, a4.y, a4.z, a4.w};
                float b[4] = {b4.x, b4.y, b4.z, b4.w};
#pragma unroll
                for (int i = 0; i < 4; i++)
#pragma unroll
                    for (int j = 0; j < 4; j++) acc[i][j] += a[i] * b[j];
            }
            __syncthreads();
        }
#pragma unroll
        for (int i = 0; i < 4; i++) {
            uint2 o;
            o.x = (u32)f2bf(acc[i][0]) | ((u32)f2bf(acc[i][1]) << 16);
            o.y = (u32)f2bf(acc[i][2]) | ((u32)f2bf(acc[i][3]) << 16);
            *(uint2*)&Bm[(size_t)(m0 + ty * 4 + i) * DD + n0 + tx * 4] = o;
        }
    } else if (bid < 320) {
        // ---- misc branch: cast Wv (rows 512..1023 of Bmat), zero S
        int g = bid - 64;                    // 0..255
        int i4 = g * 256 + tid;              // float4 index over 512*512
        float4 w = ((const float4*)Wv)[i4];
        ushort4 o;
        o.x = f2bf(w.x); o.y = f2bf(w.y); o.z = f2bf(w.z); o.w = f2bf(w.w);
        ((ushort4*)(Bm + DD * DD))[i4] = o;
        if (i4 < 8200)                       // 32800 floats = 8200 float4
            ((float4*)S)[i4] = make_float4(0.f, 0.f, 0.f, 0.f);
    } else {
        // ---- transpose branch: x fp32 -> XB bf16 row-major + XTB bf16 transposed
        // 64x64 tile, float4 loads, uint2/uint4 packed stores.
        int tb = bid - 320;                  // 0..4095
        int bx = tb & 7;                     // d-tile (8 x 64)
        int by = (tb >> 3) & 31;             // t-tile (32 x 64)
        int bz = tb >> 8;                    // batch
        u16 (*tile)[72] = (u16(*)[72])sh;    // [d_local][t_local], pitch 72 u16 = 9216 B
        int tx = tid & 15, ty = tid >> 4;    // tx: float4-col in d, ty: row in t
        int d0 = bx * 64, t0 = by * 64;
        const float* ip = x + ((size_t)bz * LL + t0) * DD + d0;
        u16* xbp = xb + ((size_t)bz * LL + t0) * DD + d0;
#pragma unroll
        for (int i = 0; i < 4; i++) {
            int r = ty + 16 * i;
            float4 v = *(const float4*)&ip[(size_t)r * DD + tx * 4];
            uint2 o;
            o.x = (u32)f2bf(v.x) | ((u32)f2bf(v.y) << 16);
            o.y = (u32)f2bf(v.z) | ((u32)f2bf(v.w) << 16);
            *(uint2*)&xbp[(size_t)r * DD + tx * 4] = o;
            tile[tx * 4 + 0][r] = (u16)(o.x);
            tile[tx * 4 + 1][r] = (u16)(o.x >> 16);
            tile[tx * 4 + 2][r] = (u16)(o.y);
            tile[tx * 4 + 3][r] = (u16)(o.y >> 16);
        }
        __syncthreads();
        u16* xtp = xtb + ((size_t)bz * DD + d0) * LL + t0;
#pragma unroll
        for (int i = 0; i < 2; i++) {
            int idx = tid + 256 * i;         // 0..511
            int dr = idx >> 3;               // d row 0..63
            int ch = idx & 7;                // 8-wide t chunk
            uint4 o = *(const uint4*)&tile[dr][ch * 8];
            *(uint4*)&xtp[(size_t)dr * LL + ch * 8] = o;
        }
    }
}

// ---------------------------------------------------------------------------
// G = XB * M^T (bf16 MFMA), written transposed bf16 GTB[b][d][t].
__global__ __launch_bounds__(256, 2) void k_gemm2(const u16* __restrict__ Ab,
                                                  const u16* __restrict__ Bm,
                                                  u16* __restrict__ GTB) {
    __shared__ u16 smem[16384];
    u16* As = smem;
    u16* Bs = smem + 8192;
    int t = threadIdx.x;
    int wave = t >> 6, lane = t & 63;
    int l15 = lane & 15, l4 = lane >> 4;
    int qr = wave & 1, qc = wave >> 1;
    int m0 = blockIdx.x * 128, n0 = blockIdx.y * 128;

    f32x4 acc[4][4];
#pragma unroll
    for (int i = 0; i < 4; i++)
#pragma unroll
        for (int j = 0; j < 4; j++) acc[i][j] = (f32x4){0.f, 0.f, 0.f, 0.f};

    const u16* Ag = Ab + (size_t)m0 * DD;
    const u16* Bg = Bm + (size_t)n0 * DD;
    int a_base = (qr * 64 + l15) * 64 + l4 * 8;
    int b_base = (qc * 64 + l15) * 64 + l4 * 8;

    for (int k0 = 0; k0 < DD; k0 += 64) {
#pragma unroll
        for (int n = 0; n < 4; n++) {
            int c = wave * 256 + n * 64 + lane;
            int row = c >> 3, col = (c & 7) * 8;
            gload16(Ag + (size_t)row * DD + k0 + col, (char*)As + (size_t)(wave * 256 + n * 64) * 16);
            gload16(Bg + (size_t)row * DD + k0 + col, (char*)Bs + (size_t)(wave * 256 + n * 64) * 16);
        }
        __syncthreads();
#pragma unroll
        for (int kk = 0; kk < 64; kk += 32) {
            bf16x8 af[4], bq[4];
#pragma unroll
            for (int i = 0; i < 4; i++) af[i] = *(const bf16x8*)(As + a_base + i * 1024 + kk);
#pragma unroll
            for (int j = 0; j < 4; j++) bq[j] = *(const bf16x8*)(Bs + b_base + j * 1024 + kk);
#pragma unroll
            for (int i = 0; i < 4; i++)
#pragma unroll
                for (int j = 0; j < 4; j++)
                    acc[i][j] = __builtin_amdgcn_mfma_f32_16x16x32_bf16(af[i], bq[j], acc[i][j], 0, 0, 0);
        }
        __syncthreads();
    }

    // Epilogue: transposed bf16 write via swizzled LDS staging
    float4* tb4 = (float4*)smem;
    int bidx = m0 >> 11;
    int tbase = m0 & 2047;
#pragma unroll
    for (int p = 0; p < 2; p++) {
        __syncthreads();
        if (qc == p) {
#pragma unroll
            for (int j = 0; j < 4; j++) {
                int nloc = j * 16 + l15;
#pragma unroll
                for (int i = 0; i < 4; i++) {
                    int tq = qr * 16 + i * 4 + l4;
                    tb4[nloc * 32 + (tq ^ (nloc & 31))] = *(float4*)&acc[i][j];
                }
            }
        }
        __syncthreads();
#pragma unroll
        for (int u = 0; u < 8; u++) {
            int idx4 = u * 256 + t;
            int nloc = idx4 >> 5, c4 = idx4 & 31;
            float4 v = tb4[nloc * 32 + (c4 ^ (nloc & 31))];
            uint2 o;
            o.x = (u32)f2bf(v.x) | ((u32)f2bf(v.y) << 16);
            o.y = (u32)f2bf(v.z) | ((u32)f2bf(v.w) << 16);
            *(uint2*)&GTB[((size_t)bidx * DD + n0 + p * 64 + nloc) * LL + tbase + c4 * 4] = o;
        }
    }
}

// ---------------------------------------------------------------------------
// out = XC * Wv^T + bv (bf16 MFMA), row-major fp32 into d_out.
__global__ __launch_bounds__(256, 2) void k_gemm3(const u16* __restrict__ Ab,
                                                  const u16* __restrict__ Bm,
                                                  const float* __restrict__ bv,
                                                  float* __restrict__ out) {
    __shared__ u16 smem[16384];
    u16* As = smem;
    u16* Bs = smem + 8192;
    int t = threadIdx.x;
    int wave = t >> 6, lane = t & 63;
    int l15 = lane & 15, l4 = lane >> 4;
    int qr = wave & 1, qc = wave >> 1;
    int m0 = blockIdx.x * 128, n0 = blockIdx.y * 128;

    f32x4 acc[4][4];
#pragma unroll
    for (int i = 0; i < 4; i++)
#pragma unroll
        for (int j = 0; j < 4; j++) acc[i][j] = (f32x4){0.f, 0.f, 0.f, 0.f};

    const u16* Ag = Ab + (size_t)m0 * DD;
    const u16* Bg = Bm + (size_t)DD * DD + (size_t)n0 * DD;
    int a_base = (qr * 64 + l15) * 64 + l4 * 8;
    int b_base = (qc * 64 + l15) * 64 + l4 * 8;

    for (int k0 = 0; k0 < DD; k0 += 64) {
#pragma unroll
        for (int n = 0; n < 4; n++) {
            int c = wave * 256 + n * 64 + lane;
            int row = c >> 3, col = (c & 7) * 8;
            gload16(Ag + (size_t)row * DD + k0 + col, (char*)As + (size_t)(wave * 256 + n * 64) * 16);
            gload16(Bg + (size_t)row * DD + k0 + col, (char*)Bs + (size_t)(wave * 256 + n * 64) * 16);
        }
        __syncthreads();
#pragma unroll
        for (int kk = 0; kk < 64; kk += 32) {
            bf16x8 af[4], bq[4];
#pragma unroll
            for (int i = 0; i < 4; i++) af[i] = *(const bf16x8*)(As + a_base + i * 1024 + kk);
#pragma unroll
            for (int j = 0; j < 4; j++) bq[j] = *(const bf16x8*)(Bs + b_base + j * 1024 + kk);
#pragma unroll
            for (int i = 0; i < 4; i++)
#pragma unroll
                for (int j = 0; j < 4; j++)
                    acc[i][j] = __builtin_amdgcn_mfma_f32_16x16x32_bf16(af[i], bq[j], acc[i][j], 0, 0, 0);
        }
        __syncthreads();
    }

    float*  tb  = (float*)smem;
    float4* tb4 = (float4*)smem;
#pragma unroll
    for (int p = 0; p < 2; p++) {
        __syncthreads();
        if (qr == p) {
#pragma unroll
            for (int j = 0; j < 4; j++) {
                int nloc = qc * 64 + j * 16 + l15;
#pragma unroll
                for (int i = 0; i < 4; i++) {
#pragma unroll
                    for (int r = 0; r < 4; r++) {
                        int mloc = i * 16 + l4 * 4 + r;
                        int nc = ((nloc >> 2) ^ (mloc & 31)) << 2;
                        tb[mloc * 128 + nc + (nloc & 3)] = acc[i][j][r];
                    }
                }
            }
        }
        __syncthreads();
#pragma unroll
        for (int u = 0; u < 8; u++) {
            int idx4 = u * 256 + t;
            int mloc = idx4 >> 5, c4 = idx4 & 31;
            float4 v = tb4[mloc * 32 + (c4 ^ (mloc & 31))];
            float4 bias = *(const float4*)&bv[n0 + c4 * 4];
            v.x += bias.x; v.y += bias.y; v.z += bias.z; v.w += bias.w;
            *(float4*)&out[(size_t)(m0 + p * 64 + mloc) * DD + n0 + c4 * 4] = v;
        }
    }
}

// ---------------------------------------------------------------------------
// Per (b, 8-channel group): packed FFT of z = x_d + i*G_d. Radix-2 fused into
// the load phase (register twiddles, computed once); 5 radix-4 stages with a
// 512-entry LDS twiddle table (jm <= 511 always); Hermitian split accumulated
// in registers. Padded LDS P(i)=i+(i>>3) -> conflict-free.
// LDS = 40944 B -> 4 blocks/CU; grid 1024 -> full residency.
__global__ __launch_bounds__(256) void k_fft(const u16* __restrict__ XTB,
                                             const u16* __restrict__ GTB,
                                             float* __restrict__ S) {
    __shared__ float2 lds[5118];      // b1[2303] | b2[2303] | twl[512] = 40944 B
    float2* b1  = lds;
    float2* b2  = lds + 2303;
    float2* twl = lds + 4606;
    int tid = threadIdx.x;
    int grp = blockIdx.x;    // 0..63
    int b = blockIdx.y;

    // 512-entry forward twiddle table (covers all radix-4 stage jm values)
    for (int j = tid; j < 512; j += 256) {
        float sn, cs;
        sincosf(-6.283185307179586f / 2048.0f * (float)j, &sn, &cs);
        twl[j] = make_float2(cs, sn);
    }
    // radix-2 twiddles for j = 4t..4t+3 (full 0..1023 range) in registers
    float2 tw2a, tw2b, tw2c, tw2d;
    {
        float sn, cs;
        sincosf(-6.283185307179586f / 2048.0f * (float)(4 * tid + 0), &sn, &cs); tw2a = make_float2(cs, sn);
        sincosf(-6.283185307179586f / 2048.0f * (float)(4 * tid + 1), &sn, &cs); tw2b = make_float2(cs, sn);
        sincosf(-6.283185307179586f / 2048.0f * (float)(4 * tid + 2), &sn, &cs); tw2c = make_float2(cs, sn);
        sincosf(-6.283185307179586f / 2048.0f * (float)(4 * tid + 3), &sn, &cs); tw2d = make_float2(cs, sn);
    }
    __syncthreads();

    float2 sr[4];
#pragma unroll
    for (int r = 0; r < 4; r++) sr[r] = make_float2(0.f, 0.f);
    float s1024 = 0.f;

    for (int c = 0; c < 8; c++) {
        int d = grp * 8 + c;
        const u16* xp = XTB + ((size_t)b * DD + d) * LL;
        const u16* gp = GTB + ((size_t)b * DD + d) * LL;
        // fused load + radix-2: thread t handles j = 4t..4t+3 paired with +1024.
        // Writes b1[P(8t)..P(8t)+7] — contiguous 64 B (pad boundary at 9t+8).
        int j0 = 4 * tid;
        uint2 xl = *(const uint2*)&xp[j0];
        uint2 xh = *(const uint2*)&xp[j0 + 1024];
        uint2 gl = *(const uint2*)&gp[j0];
        uint2 gh = *(const uint2*)&gp[j0 + 1024];
        float2* wp = &b1[P(8 * tid)];
        {
            float2 a0 = make_float2(bf2f((u16)xl.x), bf2f((u16)gl.x));
            float2 c0 = make_float2(bf2f((u16)xh.x), bf2f((u16)gh.x));
            wp[0] = cadd(a0, c0);
            wp[1] = cmul(csub(a0, c0), tw2a);
            float2 a1 = make_float2(bf2f((u16)(xl.x >> 16)), bf2f((u16)(gl.x >> 16)));
            float2 c1 = make_float2(bf2f((u16)(xh.x >> 16)), bf2f((u16)(gh.x >> 16)));
            wp[2] = cadd(a1, c1);
            wp[3] = cmul(csub(a1, c1), tw2b);
            float2 a2 = make_float2(bf2f((u16)xl.y), bf2f((u16)gl.y));
            float2 c2 = make_float2(bf2f((u16)xh.y), bf2f((u16)gh.y));
            wp[4] = cadd(a2, c2);
            wp[5] = cmul(csub(a2, c2), tw2c);
            float2 a3 = make_float2(bf2f((u16)(xl.y >> 16)), bf2f((u16)(gl.y >> 16)));
            float2 c3 = make_float2(bf2f((u16)(xh.y >> 16)), bf2f((u16)(gh.y >> 16)));
            wp[6] = cadd(a3, c3);
            wp[7] = cmul(csub(a3, c3), tw2d);
        }
        __syncthreads();
        fft_r4_chain<1>(b1, b2, twl, tid);      // result in b2
        // Hermitian split + accumulate S += Xf * conj(Gf)  (registers)
#pragma unroll
        for (int r = 0; r < 4; r++) {
            int f = tid + 256 * r;
            float2 p = b2[P(f)];
            float2 q = b2[P((2048 - f) & 2047)];
            float ar = 0.5f * (p.x + q.x), ai = 0.5f * (p.y - q.y);
            float dr = p.x - q.x, di = p.y + q.y;
            float gr = 0.5f * di, gi = -0.5f * dr;
            sr[r].x += ar * gr + ai * gi;
            sr[r].y += ai * gr - ar * gi;
        }
        if (tid == 0) {
            float2 p = b2[P(1024)];
            s1024 += p.x * p.y;
        }
        // next load writes b1 (safe: last b1 reader barriered inside chain);
        // accumulate reads of b2 complete before next chain's first b2 write
        // (which happens after the post-r2 __syncthreads).
    }
    float* Sg = S + (size_t)b * NF * 2;
#pragma unroll
    for (int r = 0; r < 4; r++) {
        int f = tid + 256 * r;
        atomicAdd(&Sg[2 * f], sr[r].x);
        atomicAdd(&Sg[2 * f + 1], sr[r].y);
    }
    if (tid == 0) {
        atomicAdd(&Sg[2048], s1024);
    }
}

// ---------------------------------------------------------------------------
// Per batch: inverse FFT (fused-r2 load of Hermitian-extended spectrum) ->
// mean_corr, top-4, softmax.
__global__ __launch_bounds__(256) void k_topk(const float* __restrict__ S,
                                              float* __restrict__ wts,
                                              int* __restrict__ idxs) {
    __shared__ float2 lds[5118];
    float2* b1  = lds;
    float2* b2  = lds + 2303;
    float2* twl = lds + 4606;
    __shared__ float cv[2048];
    __shared__ float rv[256];
    __shared__ int ri[256];
    __shared__ float topv[TOPK];
    __shared__ int topi[TOPK];
    int tid = threadIdx.x;
    int b = blockIdx.x;
    const float* Sg = S + (size_t)b * NF * 2;

    // 512-entry inverse twiddle table
    for (int j = tid; j < 512; j += 256) {
        float sn, cs;
        sincosf(6.283185307179586f / 2048.0f * (float)j, &sn, &cs);
        twl[j] = make_float2(cs, sn);
    }
    __syncthreads();

    // fused Hermitian-extension load + radix-2 -> b1 (register twiddles)
#pragma unroll
    for (int h = 0; h < 2; h++) {
#pragma unroll
        for (int e = 0; e < 2; e++) {
            int j = 2 * tid + 512 * h + e;
            float sn, cs;
            sincosf(6.283185307179586f / 2048.0f * (float)j, &sn, &cs);   // inverse sign
            float2 T = make_float2(cs, sn);
            float2 zl = make_float2(Sg[2 * j], Sg[2 * j + 1]);            // j <= 1023
            int fh = j + 1024;
            int ms = 2048 - fh;                                           // mirror for fh>1024
            float2 zh = (fh == 1024) ? make_float2(Sg[2048], Sg[2049])
                                     : make_float2(Sg[2 * ms], -Sg[2 * ms + 1]);
            b1[P(2 * j)]     = cadd(zl, zh);
            b1[P(2 * j + 1)] = cmul(csub(zl, zh), T);
        }
    }
    __syncthreads();
    fft_r4_chain<-1>(b1, b2, twl, tid);   // result in b2
    const float scale = 1.0f / ((float)LL * (float)DD);
    for (int f = tid; f < 2048; f += 256) cv[f] = b2[P(f)].x * scale;
    __syncthreads();
    for (int r = 0; r < TOPK; r++) {
        float best = -3.0e38f;
        int bi = 0x7fffffff;
        for (int f = tid; f < 2048; f += 256) {
            bool taken = false;
            for (int q = 0; q < r; q++) taken |= (topi[q] == f);
            float v = cv[f];
            if (!taken && (v > best || (v == best && f < bi))) { best = v; bi = f; }
        }
        rv[tid] = best; ri[tid] = bi;
        __syncthreads();
        for (int s = 128; s > 0; s >>= 1) {
            if (tid < s) {
                float v2 = rv[tid + s]; int i2 = ri[tid + s];
                if (v2 > rv[tid] || (v2 == rv[tid] && i2 < ri[tid])) { rv[tid] = v2; ri[tid] = i2; }
            }
            __syncthreads();
        }
        if (tid == 0) { topv[r] = rv[0]; topi[r] = ri[0]; }
        __syncthreads();
    }
    if (tid == 0) {
        float mx = topv[0];
        float e[TOPK], sum = 0.f;
        for (int k = 0; k < TOPK; k++) { e[k] = expf(topv[k] - mx); sum += e[k]; }
        for (int k = 0; k < TOPK; k++) {
            wts[b * TOPK + k] = e[k] / sum;
            idxs[b * TOPK + k] = topi[k];
        }
    }
}

// ---------------------------------------------------------------------------
// XC[b,l,:] = round_bf16( sum_k w_k * XB[b,(l-idx_k)&2047,:] )
__global__ __launch_bounds__(128) void k_combine(const u16* __restrict__ XB,
                                                 const float* __restrict__ wts,
                                                 const int* __restrict__ idxs,
                                                 u16* __restrict__ XC) {
    int l = blockIdx.x, b = blockIdx.y;
    int t = threadIdx.x;
    const ushort4* Xb = (const ushort4*)(XB + (size_t)b * LL * DD);
    float4 acc = make_float4(0.f, 0.f, 0.f, 0.f);
#pragma unroll
    for (int k = 0; k < TOPK; k++) {
        float w = wts[b * TOPK + k];
        int r = (l - idxs[b * TOPK + k]) & (LL - 1);
        ushort4 v = Xb[(size_t)r * 128 + t];
        acc.x += w * bf2f(v.x); acc.y += w * bf2f(v.y);
        acc.z += w * bf2f(v.z); acc.w += w * bf2f(v.w);
    }
    ushort4 o;
    o.x = f2bf(acc.x); o.y = f2bf(acc.y); o.z = f2bf(acc.z); o.w = f2bf(acc.w);
    ((ushort4*)(XC + (size_t)b * LL * DD))[(size_t)l * 128 + t] = o;
}

// ---------------------------------------------------------------------------
extern "C" void kernel_launch(void* const* d_in, const int* in_sizes, int n_in,
                              void* d_out, int out_size, void* d_ws, size_t ws_size,
                              hipStream_t stream) {
    const float* x  = (const float*)d_in[0];
    const float* Wq = (const float*)d_in[1];
    const float* Wk = (const float*)d_in[3];
    const float* Wv = (const float*)d_in[5];
    const float* bv = (const float*)d_in[6];
    // bq, bk provably cancel (tau-independent shift; top-k & softmax shift-invariant)
    (void)in_sizes; (void)n_in; (void)out_size; (void)ws_size;

    float* ws  = (float*)d_ws;
    u16*   XB  = (u16*)(ws + OFF_XB);
    u16*   XTB = (u16*)(ws + OFF_XTB);
    u16*   GTB = (u16*)(ws + OFF_GTB);
    u16*   XC  = (u16*)(ws + OFF_XC);
    u16*   BM  = (u16*)(ws + OFF_BBM);
    float* S   = ws + OFF_S;
    float* wts = ws + OFF_W;
    int*   idx = (int*)(ws + OFF_I);
    float* out = (float*)d_out;

    k_pre<<<4416, 256, 0, stream>>>(x, Wq, Wk, Wv, XB, XTB, BM, S);
    k_gemm2<<<dim3((BB * LL) / 128, DD / 128), 256, 0, stream>>>(XB, BM, GTB);
    k_fft<<<dim3(64, BB), 256, 0, stream>>>(XTB, GTB, S);
    k_topk<<<BB, 256, 0, stream>>>(S, wts, idx);
    k_combine<<<dim3(LL, BB), 128, 0, stream>>>(XB, wts, idx, XC);
    k_gemm3<<<dim3((BB * LL) / 128, DD / 128), 256, 0, stream>>>(XC, BM, bv, out);
}

// Round 5
// 310.549 us; speedup vs baseline: 1.1544x; 1.0008x over previous
//
#include <hip/hip_runtime.h>
#include <math.h>

typedef unsigned short u16;
typedef unsigned int   u32;
typedef __attribute__((ext_vector_type(8))) __bf16 bf16x8;
typedef __attribute__((ext_vector_type(4))) float  f32x4;

#define BB 16
#define LL 2048
#define DD 512
#define NF 1025
#define TOPK 4

// ws layout (float-unit offsets), total ~136 MB
static const size_t OFF_XB  = 0;                         // bf16 x row-major [B*L][D]
static const size_t OFF_XTB = OFF_XB  + 8388608;         // bf16 x transposed [B][D][L]
static const size_t OFF_GTB = OFF_XTB + 8388608;         // bf16 G transposed [B][D][L]
static const size_t OFF_XC  = OFF_GTB + 8388608;         // bf16 combined x [B*L][D]
static const size_t OFF_BBM = OFF_XC  + 8388608;         // bf16 Bmat [1024][512]: 0..511=M, 512..1023=Wv
static const size_t OFF_S   = OFF_BBM + 262144;          // spectra [B][NF][2]
static const size_t OFF_W   = OFF_S   + (size_t)BB * NF * 2;
static const size_t OFF_I   = OFF_W   + BB * TOPK;

__device__ __forceinline__ u16 f2bf(float f) {
    u32 u = __float_as_uint(f);
    return (u16)((u + 0x7fffu + ((u >> 16) & 1u)) >> 16);
}
__device__ __forceinline__ float bf2f(u16 h) {
    return __uint_as_float(((u32)h) << 16);
}
__device__ __forceinline__ void gload16(const void* g, void* l) {
    __builtin_amdgcn_global_load_lds((const __attribute__((address_space(1))) void*)g,
                                     (__attribute__((address_space(3))) void*)l, 16, 0, 0);
}
__device__ __forceinline__ float2 cmul(float2 u, float2 v) {
    return make_float2(u.x * v.x - u.y * v.y, u.x * v.y + u.y * v.x);
}
__device__ __forceinline__ float2 cadd(float2 u, float2 v) { return make_float2(u.x + v.x, u.y + v.y); }
__device__ __forceinline__ float2 csub(float2 u, float2 v) { return make_float2(u.x - v.x, u.y - v.y); }

// Bank-conflict-breaking padded index (1 pad per 8 float2). Verified against
// every Stockham access: M=2 store -> 9q+s (2 lanes/bank-pair), M=8 store ->
// 36h+k == 4h+k mod 32 (2 reps/residue), all other stages consecutive. Free.
__device__ __forceinline__ int P(int i) { return i + (i >> 3); }

// ---------------------------------------------------------------------------
// Radix-4 Stockham stage. Twiddles from a 512-entry LDS table (jm <= 511
// always, since w <= 511). M=512 has jm==0 -> identity, specialized.
// (R2/R3 lesson: register-resident twiddle sets live across the barriered
//  channel loop spill to scratch -> 70-130 MB of HBM traffic. LDS table is
//  the proven-clean mechanism.)
template<int M, int SGN>
__device__ __forceinline__ void radix4(const float2* __restrict__ src,
                                       float2* __restrict__ dst,
                                       const float2* __restrict__ twl, int tid) {
#pragma unroll
    for (int r = 0; r < 2; r++) {
        int w = tid + 256 * r;
        int k = w & (M - 1);
        int jm = w - k;
        float2 a = src[P(w)], b = src[P(w + 512)], c = src[P(w + 1024)], d = src[P(w + 1536)];
        float2 t0 = cadd(a, c), t1 = csub(a, c), t2 = cadd(b, d), bd = csub(b, d);
        float2 t3 = (SGN > 0) ? make_float2(bd.y, -bd.x)
                              : make_float2(-bd.y, bd.x);
        int o = 4 * jm + k;
        if (M == 512) {
            dst[P(o)]         = cadd(t0, t2);
            dst[P(o + M)]     = cadd(t1, t3);
            dst[P(o + 2 * M)] = csub(t0, t2);
            dst[P(o + 3 * M)] = csub(t1, t3);
        } else {
            float2 T1 = twl[jm];
            float2 T2 = cmul(T1, T1);
            float2 T3 = cmul(T1, T2);
            dst[P(o)]         = cadd(t0, t2);
            dst[P(o + M)]     = cmul(cadd(t1, t3), T1);
            dst[P(o + 2 * M)] = cmul(csub(t0, t2), T2);
            dst[P(o + 3 * M)] = cmul(csub(t1, t3), T3);
        }
    }
}

// 5 radix-4 stages (input must hold the m=2 Stockham state, i.e. after the
// fused radix-2). b1 -> ... -> result in b2. Caller barriers before entry.
template<int SGN>
__device__ __forceinline__ void fft_r4_chain(float2* __restrict__ b1, float2* __restrict__ b2,
                                             const float2* __restrict__ twl, int tid) {
    radix4<2,   SGN>(b1, b2, twl, tid); __syncthreads();
    radix4<8,   SGN>(b2, b1, twl, tid); __syncthreads();
    radix4<32,  SGN>(b1, b2, twl, tid); __syncthreads();
    radix4<128, SGN>(b2, b1, twl, tid); __syncthreads();
    radix4<512, SGN>(b1, b2, twl, tid); __syncthreads();
}

// ---------------------------------------------------------------------------
// Merged prologue. Branch order matters for dispatch overlap:
//   bid 0..63    : gemm1 M = Wq^T*Wk        (latency-heavy, start FIRST)
//   bid 64..319  : cast Wv + zero S
//   bid 320..2367: transpose+cast x (64d x 128t tiles, vectorized, 8-deep MLP)
__global__ __launch_bounds__(256) void k_pre(const float* __restrict__ x,
                                             const float* __restrict__ Wq,
                                             const float* __restrict__ Wk,
                                             const float* __restrict__ Wv,
                                             u16* __restrict__ xb,
                                             u16* __restrict__ xtb,
                                             u16* __restrict__ Bm,
                                             float* __restrict__ S) {
    __shared__ char sh[17152];
    int bid = blockIdx.x;
    int tid = threadIdx.x;
    if (bid < 64) {
        // ---- gemm1 branch: M = Wq^T * Wk -> bf16 rows 0..511 of Bmat
        int g = bid;
        float (*As)[68] = (float(*)[68])sh;
        float (*Bs)[68] = (float(*)[68])(sh + 4352);
        int tx = tid & 15, ty = tid >> 4;
        int m0 = (g & 7) * 64, n0 = (g >> 3) * 64;
        float acc[4][4] = {};
        for (int k0 = 0; k0 < DD; k0 += 16) {
#pragma unroll
            for (int r = 0; r < 4; r++) {
                As[ty][tx + 16 * r] = Wq[(size_t)(k0 + ty) * DD + m0 + tx + 16 * r];
                Bs[ty][tx + 16 * r] = Wk[(size_t)(k0 + ty) * DD + n0 + tx + 16 * r];
            }
            __syncthreads();
#pragma unroll
            for (int k = 0; k < 16; k++) {
                float4 a4 = *(const float4*)&As[k][ty * 4];
                float4 b4 = *(const float4*)&Bs[k][tx * 4];
                float a[4] = {a4.x, a4.y, a4.z, a4.w};
                float b[4] = {b4.x, b4.y, b4.z, b4.w};
#pragma unroll
                for (int i = 0; i < 4; i++)
#pragma unroll
                    for (int j = 0; j < 4; j++) acc[i][j] += a[i] * b[j];
            }
            __syncthreads();
        }
#pragma unroll
        for (int i = 0; i < 4; i++) {
            uint2 o;
            o.x = (u32)f2bf(acc[i][0]) | ((u32)f2bf(acc[i][1]) << 16);
            o.y = (u32)f2bf(acc[i][2]) | ((u32)f2bf(acc[i][3]) << 16);
            *(uint2*)&Bm[(size_t)(m0 + ty * 4 + i) * DD + n0 + tx * 4] = o;
        }
    } else if (bid < 320) {
        // ---- misc branch: cast Wv (rows 512..1023 of Bmat), zero S
        int g = bid - 64;                    // 0..255
        int i4 = g * 256 + tid;              // float4 index over 512*512
        float4 w = ((const float4*)Wv)[i4];
        ushort4 o;
        o.x = f2bf(w.x); o.y = f2bf(w.y); o.z = f2bf(w.z); o.w = f2bf(w.w);
        ((ushort4*)(Bm + DD * DD))[i4] = o;
        if (i4 < 8200)                       // 32800 floats = 8200 float4
            ((float4*)S)[i4] = make_float4(0.f, 0.f, 0.f, 0.f);
    } else {
        // ---- transpose branch: x fp32 -> XB bf16 row-major + XTB bf16 transposed
        // 64d x 128t tile. 8 float4 loads hoisted (MLP=8). LDS tile stored as
        // u32 t-pairs, pitch 67 u32: b32 writes bank = (12tx+ty) -> 2-way free;
        // b32 reads bank = (3dr+4ch+e) -> 2-way free. (R4 lesson: pitch-72 u16
        // scalar writes were a 16-way conflict: 16*tx mod 32 has only 2 values.)
        int tb = bid - 320;                  // 0..2047
        int bx = tb & 7;                     // d-tile (8 x 64)
        int by = (tb >> 3) & 15;             // t-tile (16 x 128)
        int bz = tb >> 7;                    // batch
        u32* tile32 = (u32*)sh;              // [64][67] u32 = 17152 B
        int tx = tid & 15, ty = tid >> 4;
        int d0 = bx * 64, t0 = by * 128;
        const float* ip = x + ((size_t)bz * LL + t0) * DD + d0 + tx * 4;
        u16* xbp = xb + ((size_t)bz * LL + t0) * DD + d0 + tx * 4;
        float4 va[4], vb[4];
#pragma unroll
        for (int ii = 0; ii < 4; ii++) {
            int r = 2 * (ty + 16 * ii);
            va[ii] = *(const float4*)&ip[(size_t)r * DD];
            vb[ii] = *(const float4*)&ip[(size_t)(r + 1) * DD];
        }
#pragma unroll
        for (int ii = 0; ii < 4; ii++) {
            int r = 2 * (ty + 16 * ii);
            int half = ty + 16 * ii;         // r/2
            u32 ax = f2bf(va[ii].x), ay = f2bf(va[ii].y), az = f2bf(va[ii].z), aw = f2bf(va[ii].w);
            u32 bx_ = f2bf(vb[ii].x), by_ = f2bf(vb[ii].y), bz_ = f2bf(vb[ii].z), bw_ = f2bf(vb[ii].w);
            uint2 oa, ob;
            oa.x = ax | (ay << 16); oa.y = az | (aw << 16);
            ob.x = bx_ | (by_ << 16); ob.y = bz_ | (bw_ << 16);
            *(uint2*)&xbp[(size_t)r * DD] = oa;
            *(uint2*)&xbp[(size_t)(r + 1) * DD] = ob;
            // LDS: word [d-row][t-pair] = (bf16(t=2h) | bf16(t=2h+1)<<16)
            tile32[(4 * tx + 0) * 67 + half] = ax | (bx_ << 16);
            tile32[(4 * tx + 1) * 67 + half] = ay | (by_ << 16);
            tile32[(4 * tx + 2) * 67 + half] = az | (bz_ << 16);
            tile32[(4 * tx + 3) * 67 + half] = aw | (bw_ << 16);
        }
        __syncthreads();
        u16* xtp = xtb + ((size_t)bz * DD + d0) * LL + t0;
#pragma unroll
        for (int u = 0; u < 4; u++) {
            int idx = u * 256 + tid;         // 0..1023
            int dr = idx >> 4;               // d row 0..63
            int ch = idx & 15;               // 8-wide t chunk
            const u32* rp = tile32 + dr * 67 + ch * 4;
            uint4 o = make_uint4(rp[0], rp[1], rp[2], rp[3]);
            *(uint4*)&xtp[(size_t)dr * LL + ch * 8] = o;
        }
    }
}

// ---------------------------------------------------------------------------
// G = XB * M^T (bf16 MFMA), written transposed bf16 GTB[b][d][t].
__global__ __launch_bounds__(256, 2) void k_gemm2(const u16* __restrict__ Ab,
                                                  const u16* __restrict__ Bm,
                                                  u16* __restrict__ GTB) {
    __shared__ u16 smem[16384];
    u16* As = smem;
    u16* Bs = smem + 8192;
    int t = threadIdx.x;
    int wave = t >> 6, lane = t & 63;
    int l15 = lane & 15, l4 = lane >> 4;
    int qr = wave & 1, qc = wave >> 1;
    int m0 = blockIdx.x * 128, n0 = blockIdx.y * 128;

    f32x4 acc[4][4];
#pragma unroll
    for (int i = 0; i < 4; i++)
#pragma unroll
        for (int j = 0; j < 4; j++) acc[i][j] = (f32x4){0.f, 0.f, 0.f, 0.f};

    const u16* Ag = Ab + (size_t)m0 * DD;
    const u16* Bg = Bm + (size_t)n0 * DD;
    int a_base = (qr * 64 + l15) * 64 + l4 * 8;
    int b_base = (qc * 64 + l15) * 64 + l4 * 8;

    for (int k0 = 0; k0 < DD; k0 += 64) {
#pragma unroll
        for (int n = 0; n < 4; n++) {
            int c = wave * 256 + n * 64 + lane;
            int row = c >> 3, col = (c & 7) * 8;
            gload16(Ag + (size_t)row * DD + k0 + col, (char*)As + (size_t)(wave * 256 + n * 64) * 16);
            gload16(Bg + (size_t)row * DD + k0 + col, (char*)Bs + (size_t)(wave * 256 + n * 64) * 16);
        }
        __syncthreads();
#pragma unroll
        for (int kk = 0; kk < 64; kk += 32) {
            bf16x8 af[4], bq[4];
#pragma unroll
            for (int i = 0; i < 4; i++) af[i] = *(const bf16x8*)(As + a_base + i * 1024 + kk);
#pragma unroll
            for (int j = 0; j < 4; j++) bq[j] = *(const bf16x8*)(Bs + b_base + j * 1024 + kk);
#pragma unroll
            for (int i = 0; i < 4; i++)
#pragma unroll
                for (int j = 0; j < 4; j++)
                    acc[i][j] = __builtin_amdgcn_mfma_f32_16x16x32_bf16(af[i], bq[j], acc[i][j], 0, 0, 0);
        }
        __syncthreads();
    }

    // Epilogue: transposed bf16 write via swizzled LDS staging
    float4* tb4 = (float4*)smem;
    int bidx = m0 >> 11;
    int tbase = m0 & 2047;
#pragma unroll
    for (int p = 0; p < 2; p++) {
        __syncthreads();
        if (qc == p) {
#pragma unroll
            for (int j = 0; j < 4; j++) {
                int nloc = j * 16 + l15;
#pragma unroll
                for (int i = 0; i < 4; i++) {
                    int tq = qr * 16 + i * 4 + l4;
                    tb4[nloc * 32 + (tq ^ (nloc & 31))] = *(float4*)&acc[i][j];
                }
            }
        }
        __syncthreads();
#pragma unroll
        for (int u = 0; u < 8; u++) {
            int idx4 = u * 256 + t;
            int nloc = idx4 >> 5, c4 = idx4 & 31;
            float4 v = tb4[nloc * 32 + (c4 ^ (nloc & 31))];
            uint2 o;
            o.x = (u32)f2bf(v.x) | ((u32)f2bf(v.y) << 16);
            o.y = (u32)f2bf(v.z) | ((u32)f2bf(v.w) << 16);
            *(uint2*)&GTB[((size_t)bidx * DD + n0 + p * 64 + nloc) * LL + tbase + c4 * 4] = o;
        }
    }
}

// ---------------------------------------------------------------------------
// out = XC * Wv^T + bv (bf16 MFMA), row-major fp32 into d_out.
__global__ __launch_bounds__(256, 2) void k_gemm3(const u16* __restrict__ Ab,
                                                  const u16* __restrict__ Bm,
                                                  const float* __restrict__ bv,
                                                  float* __restrict__ out) {
    __shared__ u16 smem[16384];
    u16* As = smem;
    u16* Bs = smem + 8192;
    int t = threadIdx.x;
    int wave = t >> 6, lane = t & 63;
    int l15 = lane & 15, l4 = lane >> 4;
    int qr = wave & 1, qc = wave >> 1;
    int m0 = blockIdx.x * 128, n0 = blockIdx.y * 128;

    f32x4 acc[4][4];
#pragma unroll
    for (int i = 0; i < 4; i++)
#pragma unroll
        for (int j = 0; j < 4; j++) acc[i][j] = (f32x4){0.f, 0.f, 0.f, 0.f};

    const u16* Ag = Ab + (size_t)m0 * DD;
    const u16* Bg = Bm + (size_t)DD * DD + (size_t)n0 * DD;
    int a_base = (qr * 64 + l15) * 64 + l4 * 8;
    int b_base = (qc * 64 + l15) * 64 + l4 * 8;

    for (int k0 = 0; k0 < DD; k0 += 64) {
#pragma unroll
        for (int n = 0; n < 4; n++) {
            int c = wave * 256 + n * 64 + lane;
            int row = c >> 3, col = (c & 7) * 8;
            gload16(Ag + (size_t)row * DD + k0 + col, (char*)As + (size_t)(wave * 256 + n * 64) * 16);
            gload16(Bg + (size_t)row * DD + k0 + col, (char*)Bs + (size_t)(wave * 256 + n * 64) * 16);
        }
        __syncthreads();
#pragma unroll
        for (int kk = 0; kk < 64; kk += 32) {
            bf16x8 af[4], bq[4];
#pragma unroll
            for (int i = 0; i < 4; i++) af[i] = *(const bf16x8*)(As + a_base + i * 1024 + kk);
#pragma unroll
            for (int j = 0; j < 4; j++) bq[j] = *(const bf16x8*)(Bs + b_base + j * 1024 + kk);
#pragma unroll
            for (int i = 0; i < 4; i++)
#pragma unroll
                for (int j = 0; j < 4; j++)
                    acc[i][j] = __builtin_amdgcn_mfma_f32_16x16x32_bf16(af[i], bq[j], acc[i][j], 0, 0, 0);
        }
        __syncthreads();
    }

    float*  tb  = (float*)smem;
    float4* tb4 = (float4*)smem;
#pragma unroll
    for (int p = 0; p < 2; p++) {
        __syncthreads();
        if (qr == p) {
#pragma unroll
            for (int j = 0; j < 4; j++) {
                int nloc = qc * 64 + j * 16 + l15;
#pragma unroll
                for (int i = 0; i < 4; i++) {
#pragma unroll
                    for (int r = 0; r < 4; r++) {
                        int mloc = i * 16 + l4 * 4 + r;
                        int nc = ((nloc >> 2) ^ (mloc & 31)) << 2;
                        tb[mloc * 128 + nc + (nloc & 3)] = acc[i][j][r];
                    }
                }
            }
        }
        __syncthreads();
#pragma unroll
        for (int u = 0; u < 8; u++) {
            int idx4 = u * 256 + t;
            int mloc = idx4 >> 5, c4 = idx4 & 31;
            float4 v = tb4[mloc * 32 + (c4 ^ (mloc & 31))];
            float4 bias = *(const float4*)&bv[n0 + c4 * 4];
            v.x += bias.x; v.y += bias.y; v.z += bias.z; v.w += bias.w;
            *(float4*)&out[(size_t)(m0 + p * 64 + mloc) * DD + n0 + c4 * 4] = v;
        }
    }
}

// ---------------------------------------------------------------------------
// Per (b, 8-channel group): packed FFT of z = x_d + i*G_d. Radix-2 fused into
// the load phase (register twiddles, computed once); 5 radix-4 stages with a
// 512-entry LDS twiddle table (jm <= 511 always); Hermitian split accumulated
// in registers. Padded LDS P(i)=i+(i>>3) -> conflict-free.
// LDS = 40944 B -> 4 blocks/CU; grid 1024 -> full residency.
__global__ __launch_bounds__(256) void k_fft(const u16* __restrict__ XTB,
                                             const u16* __restrict__ GTB,
                                             float* __restrict__ S) {
    __shared__ float2 lds[5118];      // b1[2303] | b2[2303] | twl[512] = 40944 B
    float2* b1  = lds;
    float2* b2  = lds + 2303;
    float2* twl = lds + 4606;
    int tid = threadIdx.x;
    int grp = blockIdx.x;    // 0..63
    int b = blockIdx.y;

    // 512-entry forward twiddle table (covers all radix-4 stage jm values)
    for (int j = tid; j < 512; j += 256) {
        float sn, cs;
        sincosf(-6.283185307179586f / 2048.0f * (float)j, &sn, &cs);
        twl[j] = make_float2(cs, sn);
    }
    // radix-2 twiddles for j = 4t..4t+3 (full 0..1023 range) in registers
    float2 tw2a, tw2b, tw2c, tw2d;
    {
        float sn, cs;
        sincosf(-6.283185307179586f / 2048.0f * (float)(4 * tid + 0), &sn, &cs); tw2a = make_float2(cs, sn);
        sincosf(-6.283185307179586f / 2048.0f * (float)(4 * tid + 1), &sn, &cs); tw2b = make_float2(cs, sn);
        sincosf(-6.283185307179586f / 2048.0f * (float)(4 * tid + 2), &sn, &cs); tw2c = make_float2(cs, sn);
        sincosf(-6.283185307179586f / 2048.0f * (float)(4 * tid + 3), &sn, &cs); tw2d = make_float2(cs, sn);
    }
    __syncthreads();

    float2 sr[4];
#pragma unroll
    for (int r = 0; r < 4; r++) sr[r] = make_float2(0.f, 0.f);
    float s1024 = 0.f;

    for (int c = 0; c < 8; c++) {
        int d = grp * 8 + c;
        const u16* xp = XTB + ((size_t)b * DD + d) * LL;
        const u16* gp = GTB + ((size_t)b * DD + d) * LL;
        // fused load + radix-2: thread t handles j = 4t..4t+3 paired with +1024.
        // Writes b1[P(8t)..P(8t)+7] — contiguous 64 B (pad boundary at 9t+8).
        int j0 = 4 * tid;
        uint2 xl = *(const uint2*)&xp[j0];
        uint2 xh = *(const uint2*)&xp[j0 + 1024];
        uint2 gl = *(const uint2*)&gp[j0];
        uint2 gh = *(const uint2*)&gp[j0 + 1024];
        float2* wp = &b1[P(8 * tid)];
        {
            float2 a0 = make_float2(bf2f((u16)xl.x), bf2f((u16)gl.x));
            float2 c0 = make_float2(bf2f((u16)xh.x), bf2f((u16)gh.x));
            wp[0] = cadd(a0, c0);
            wp[1] = cmul(csub(a0, c0), tw2a);
            float2 a1 = make_float2(bf2f((u16)(xl.x >> 16)), bf2f((u16)(gl.x >> 16)));
            float2 c1 = make_float2(bf2f((u16)(xh.x >> 16)), bf2f((u16)(gh.x >> 16)));
            wp[2] = cadd(a1, c1);
            wp[3] = cmul(csub(a1, c1), tw2b);
            float2 a2 = make_float2(bf2f((u16)xl.y), bf2f((u16)gl.y));
            float2 c2 = make_float2(bf2f((u16)xh.y), bf2f((u16)gh.y));
            wp[4] = cadd(a2, c2);
            wp[5] = cmul(csub(a2, c2), tw2c);
            float2 a3 = make_float2(bf2f((u16)(xl.y >> 16)), bf2f((u16)(gl.y >> 16)));
            float2 c3 = make_float2(bf2f((u16)(xh.y >> 16)), bf2f((u16)(gh.y >> 16)));
            wp[6] = cadd(a3, c3);
            wp[7] = cmul(csub(a3, c3), tw2d);
        }
        __syncthreads();
        fft_r4_chain<1>(b1, b2, twl, tid);      // result in b2
        // Hermitian split + accumulate S += Xf * conj(Gf)  (registers)
#pragma unroll
        for (int r = 0; r < 4; r++) {
            int f = tid + 256 * r;
            float2 p = b2[P(f)];
            float2 q = b2[P((2048 - f) & 2047)];
            float ar = 0.5f * (p.x + q.x), ai = 0.5f * (p.y - q.y);
            float dr = p.x - q.x, di = p.y + q.y;
            float gr = 0.5f * di, gi = -0.5f * dr;
            sr[r].x += ar * gr + ai * gi;
            sr[r].y += ai * gr - ar * gi;
        }
        if (tid == 0) {
            float2 p = b2[P(1024)];
            s1024 += p.x * p.y;
        }
        // next load writes b1 (safe: last b1 reader barriered inside chain);
        // accumulate reads of b2 complete before next chain's first b2 write
        // (which happens after the post-r2 __syncthreads).
    }
    float* Sg = S + (size_t)b * NF * 2;
#pragma unroll
    for (int r = 0; r < 4; r++) {
        int f = tid + 256 * r;
        atomicAdd(&Sg[2 * f], sr[r].x);
        atomicAdd(&Sg[2 * f + 1], sr[r].y);
    }
    if (tid == 0) {
        atomicAdd(&Sg[2048], s1024);
    }
}

// ---------------------------------------------------------------------------
// Per batch: inverse FFT (fused-r2 load of Hermitian-extended spectrum) ->
// mean_corr, top-4, softmax.
__global__ __launch_bounds__(256) void k_topk(const float* __restrict__ S,
                                              float* __restrict__ wts,
                                              int* __restrict__ idxs) {
    __shared__ float2 lds[5118];
    float2* b1  = lds;
    float2* b2  = lds + 2303;
    float2* twl = lds + 4606;
    __shared__ float cv[2048];
    __shared__ float rv[256];
    __shared__ int ri[256];
    __shared__ float topv[TOPK];
    __shared__ int topi[TOPK];
    int tid = threadIdx.x;
    int b = blockIdx.x;
    const float* Sg = S + (size_t)b * NF * 2;

    // 512-entry inverse twiddle table
    for (int j = tid; j < 512; j += 256) {
        float sn, cs;
        sincosf(6.283185307179586f / 2048.0f * (float)j, &sn, &cs);
        twl[j] = make_float2(cs, sn);
    }
    __syncthreads();

    // fused Hermitian-extension load + radix-2 -> b1 (register twiddles)
#pragma unroll
    for (int h = 0; h < 2; h++) {
#pragma unroll
        for (int e = 0; e < 2; e++) {
            int j = 2 * tid + 512 * h + e;
            float sn, cs;
            sincosf(6.283185307179586f / 2048.0f * (float)j, &sn, &cs);   // inverse sign
            float2 T = make_float2(cs, sn);
            float2 zl = make_float2(Sg[2 * j], Sg[2 * j + 1]);            // j <= 1023
            int fh = j + 1024;
            int ms = 2048 - fh;                                           // mirror for fh>1024
            float2 zh = (fh == 1024) ? make_float2(Sg[2048], Sg[2049])
                                     : make_float2(Sg[2 * ms], -Sg[2 * ms + 1]);
            b1[P(2 * j)]     = cadd(zl, zh);
            b1[P(2 * j + 1)] = cmul(csub(zl, zh), T);
        }
    }
    __syncthreads();
    fft_r4_chain<-1>(b1, b2, twl, tid);   // result in b2
    const float scale = 1.0f / ((float)LL * (float)DD);
    for (int f = tid; f < 2048; f += 256) cv[f] = b2[P(f)].x * scale;
    __syncthreads();
    for (int r = 0; r < TOPK; r++) {
        float best = -3.0e38f;
        int bi = 0x7fffffff;
        for (int f = tid; f < 2048; f += 256) {
            bool taken = false;
            for (int q = 0; q < r; q++) taken |= (topi[q] == f);
            float v = cv[f];
            if (!taken && (v > best || (v == best && f < bi))) { best = v; bi = f; }
        }
        rv[tid] = best; ri[tid] = bi;
        __syncthreads();
        for (int s = 128; s > 0; s >>= 1) {
            if (tid < s) {
                float v2 = rv[tid + s]; int i2 = ri[tid + s];
                if (v2 > rv[tid] || (v2 == rv[tid] && i2 < ri[tid])) { rv[tid] = v2; ri[tid] = i2; }
            }
            __syncthreads();
        }
        if (tid == 0) { topv[r] = rv[0]; topi[r] = ri[0]; }
        __syncthreads();
    }
    if (tid == 0) {
        float mx = topv[0];
        float e[TOPK], sum = 0.f;
        for (int k = 0; k < TOPK; k++) { e[k] = expf(topv[k] - mx); sum += e[k]; }
        for (int k = 0; k < TOPK; k++) {
            wts[b * TOPK + k] = e[k] / sum;
            idxs[b * TOPK + k] = topi[k];
        }
    }
}

// ---------------------------------------------------------------------------
// XC[b,l,:] = round_bf16( sum_k w_k * XB[b,(l-idx_k)&2047,:] )
__global__ __launch_bounds__(128) void k_combine(const u16* __restrict__ XB,
                                                 const float* __restrict__ wts,
                                                 const int* __restrict__ idxs,
                                                 u16* __restrict__ XC) {
    int l = blockIdx.x, b = blockIdx.y;
    int t = threadIdx.x;
    const ushort4* Xb = (const ushort4*)(XB + (size_t)b * LL * DD);
    float4 acc = make_float4(0.f, 0.f, 0.f, 0.f);
#pragma unroll
    for (int k = 0; k < TOPK; k++) {
        float w = wts[b * TOPK + k];
        int r = (l - idxs[b * TOPK + k]) & (LL - 1);
        ushort4 v = Xb[(size_t)r * 128 + t];
        acc.x += w * bf2f(v.x); acc.y += w * bf2f(v.y);
        acc.z += w * bf2f(v.z); acc.w += w * bf2f(v.w);
    }
    ushort4 o;
    o.x = f2bf(acc.x); o.y = f2bf(acc.y); o.z = f2bf(acc.z); o.w = f2bf(acc.w);
    ((ushort4*)(XC + (size_t)b * LL * DD))[(size_t)l * 128 + t] = o;
}

// ---------------------------------------------------------------------------
extern "C" void kernel_launch(void* const* d_in, const int* in_sizes, int n_in,
                              void* d_out, int out_size, void* d_ws, size_t ws_size,
                              hipStream_t stream) {
    const float* x  = (const float*)d_in[0];
    const float* Wq = (const float*)d_in[1];
    const float* Wk = (const float*)d_in[3];
    const float* Wv = (const float*)d_in[5];
    const float* bv = (const float*)d_in[6];
    // bq, bk provably cancel (tau-independent shift; top-k & softmax shift-invariant)
    (void)in_sizes; (void)n_in; (void)out_size; (void)ws_size;

    float* ws  = (float*)d_ws;
    u16*   XB  = (u16*)(ws + OFF_XB);
    u16*   XTB = (u16*)(ws + OFF_XTB);
    u16*   GTB = (u16*)(ws + OFF_GTB);
    u16*   XC  = (u16*)(ws + OFF_XC);
    u16*   BM  = (u16*)(ws + OFF_BBM);
    float* S   = ws + OFF_S;
    float* wts = ws + OFF_W;
    int*   idx = (int*)(ws + OFF_I);
    float* out = (float*)d_out;

    k_pre<<<2368, 256, 0, stream>>>(x, Wq, Wk, Wv, XB, XTB, BM, S);
    k_gemm2<<<dim3((BB * LL) / 128, DD / 128), 256, 0, stream>>>(XB, BM, GTB);
    k_fft<<<dim3(64, BB), 256, 0, stream>>>(XTB, GTB, S);
    k_topk<<<BB, 256, 0, stream>>>(S, wts, idx);
    k_combine<<<dim3(LL, BB), 128, 0, stream>>>(XB, wts, idx, XC);
    k_gemm3<<<dim3((BB * LL) / 128, DD / 128), 256, 0, stream>>>(XC, BM, bv, out);
}